// Round 1
// baseline (1537.035 us; speedup 1.0000x reference)
//
#include <hip/hip_runtime.h>
#include <hip/hip_bf16.h>

using bf16 = __hip_bfloat16;
typedef __bf16 bf16x8 __attribute__((ext_vector_type(8)));
typedef float f32x4 __attribute__((ext_vector_type(4)));

#define MROWS 100352   // 2048 windows * 49 tokens = 32*3136

__device__ __forceinline__ void async16(void* l, const void* g) {
    void* gg = const_cast<void*>(g);
    __builtin_amdgcn_global_load_lds((__attribute__((address_space(1))) void*)gg,
                                     (__attribute__((address_space(3))) void*)l, 16, 0, 0);
}

__global__ __launch_bounds__(256) void f32_to_bf16_k(const float* __restrict__ s,
                                                     bf16* __restrict__ d, int n) {
    int i = blockIdx.x * 256 + threadIdx.x;
    if (i < n) d[i] = __float2bfloat16(s[i]);
}

// LN1 + cyclic shift(-3,-3) + window partition. One wave per output row.
__global__ __launch_bounds__(256) void ln1_window_k(const float* __restrict__ x,
                                                    const float* __restrict__ g,
                                                    const float* __restrict__ bta,
                                                    bf16* __restrict__ ywin) {
    int wrow = blockIdx.x * 4 + (threadIdx.x >> 6);
    int lane = threadIdx.x & 63;
    int tok = wrow % 49, win = wrow / 49;
    int i = tok / 7, j = tok % 7;
    int wwi = win & 7, whi = (win >> 3) & 7, bi = win >> 6;
    int hs = (whi * 7 + i + 3) % 56;
    int ws_ = (wwi * 7 + j + 3) % 56;
    const float* xr = x + ((size_t)bi * 3136 + (size_t)hs * 56 + ws_) * 384;
    float v[6]; float s = 0.f, s2 = 0.f;
#pragma unroll
    for (int u = 0; u < 6; ++u) { float t = xr[lane + 64 * u]; v[u] = t; s += t; s2 += t * t; }
#pragma unroll
    for (int d = 1; d < 64; d <<= 1) { s += __shfl_xor(s, d); s2 += __shfl_xor(s2, d); }
    float mean = s * (1.0f / 384.0f);
    float var = s2 * (1.0f / 384.0f) - mean * mean;
    float rstd = rsqrtf(var + 1e-5f);
    bf16* yr = ywin + (size_t)wrow * 384;
#pragma unroll
    for (int u = 0; u < 6; ++u) {
        int c = lane + 64 * u;
        yr[c] = __float2bfloat16((v[u] - mean) * rstd * g[c] + bta[c]);
    }
}

// residual add (window-reverse + roll(+3,+3)) + LN2. x2 -> d_out (fp32), z -> bf16
__global__ __launch_bounds__(256) void resid_ln2_k(const float* __restrict__ x,
                                                   const bf16* __restrict__ proj,
                                                   const float* __restrict__ g,
                                                   const float* __restrict__ bta,
                                                   float* __restrict__ x2,
                                                   bf16* __restrict__ z) {
    int row = blockIdx.x * 4 + (threadIdx.x >> 6);
    int lane = threadIdx.x & 63;
    int bi = row / 3136; int hw = row % 3136;
    int h = hw / 56, w = hw % 56;
    int h2 = (h + 53) % 56, w2 = (w + 53) % 56;
    int prow = ((bi * 8 + h2 / 7) * 8 + w2 / 7) * 49 + (h2 % 7) * 7 + (w2 % 7);
    const float* xr = x + (size_t)row * 384;
    const bf16* pr = proj + (size_t)prow * 384;
    float* x2r = x2 + (size_t)row * 384;
    float v[6]; float s = 0.f, s2 = 0.f;
#pragma unroll
    for (int u = 0; u < 6; ++u) {
        int c = lane + 64 * u;
        float t = xr[c] + __bfloat162float(pr[c]);
        v[u] = t; s += t; s2 += t * t;
        x2r[c] = t;
    }
#pragma unroll
    for (int d = 1; d < 64; d <<= 1) { s += __shfl_xor(s, d); s2 += __shfl_xor(s2, d); }
    float mean = s * (1.0f / 384.0f);
    float var = s2 * (1.0f / 384.0f) - mean * mean;
    float rstd = rsqrtf(var + 1e-5f);
    bf16* zr = z + (size_t)row * 384;
#pragma unroll
    for (int u = 0; u < 6; ++u) {
        int c = lane + 64 * u;
        zr[c] = __float2bfloat16((v[u] - mean) * rstd * g[c] + bta[c]);
    }
}

// windowed attention: one block per (window, head)
__global__ __launch_bounds__(256) void attn_k(const bf16* __restrict__ qkv,
                                              const float* __restrict__ rpbt,
                                              bf16* __restrict__ o) {
    __shared__ float qs[49][33], ks[49][33], vs[49][33], S[49][50];
    int blk = blockIdx.x;
    int win = blk / 12, hh = blk % 12;
    int wi = win & 63;
    int whi = wi >> 3, wwi = wi & 7;
    int tid = threadIdx.x;
    const size_t base = (size_t)win * 49 * 1152 + hh * 32;
    for (int idx = tid; idx < 1568; idx += 256) {
        int n = idx >> 5, d = idx & 31;
        size_t rowb = base + (size_t)n * 1152;
        qs[n][d] = __bfloat162float(qkv[rowb + d]) * 0.17677669529663687f;
        ks[n][d] = __bfloat162float(qkv[rowb + 384 + d]);
        vs[n][d] = __bfloat162float(qkv[rowb + 768 + d]);
    }
    __syncthreads();
    for (int idx = tid; idx < 2401; idx += 256) {
        int n = idx / 49, m = idx % 49;
        float acc = 0.f;
#pragma unroll
        for (int d = 0; d < 32; ++d) acc += qs[n][d] * ks[m][d];
        int i1 = n / 7, j1 = n % 7, i2 = m / 7, j2 = m % 7;
        int ridx = (i1 - i2 + 6) * 13 + (j1 - j2 + 6);
        acc += rpbt[ridx * 12 + hh];
        int hn = whi * 7 + i1, wn = wwi * 7 + j1;
        int hm = whi * 7 + i2, wm = wwi * 7 + j2;
        int rn = (hn < 49 ? 0 : (hn < 53 ? 1 : 2)) * 3 + (wn < 49 ? 0 : (wn < 53 ? 1 : 2));
        int rm = (hm < 49 ? 0 : (hm < 53 ? 1 : 2)) * 3 + (wm < 49 ? 0 : (wm < 53 ? 1 : 2));
        if (rn != rm) acc -= 100.0f;
        S[n][m] = acc;
    }
    __syncthreads();
    int wave = tid >> 6, lane = tid & 63;
    for (int r = wave; r < 49; r += 4) {
        float val = (lane < 49) ? S[r][lane] : -1e30f;
        float mx = val;
#pragma unroll
        for (int d = 1; d < 64; d <<= 1) mx = fmaxf(mx, __shfl_xor(mx, d));
        float e = (lane < 49) ? expf(val - mx) : 0.0f;
        float sum = e;
#pragma unroll
        for (int d = 1; d < 64; d <<= 1) sum += __shfl_xor(sum, d);
        if (lane < 49) S[r][lane] = e / sum;
    }
    __syncthreads();
    for (int idx = tid; idx < 1568; idx += 256) {
        int n = idx >> 5, d = idx & 31;
        float acc = 0.f;
#pragma unroll
        for (int m = 0; m < 49; ++m) acc += S[n][m] * vs[m][d];
        o[(size_t)(win * 49 + n) * 384 + hh * 32 + d] = __float2bfloat16(acc);
    }
}

// C[M,N] = A[M,K] (bf16, row-major) @ W[N,K]^T (bf16, row-major) [+ bias][+ gelu | + inplace f32 add]
// EPI: 0 = store bf16 (+bias if given); 1 = bias+gelu -> bf16; 2 = bias + inplace add into f32 Cout
template <int EPI>
__global__ __launch_bounds__(256) void gemm_bt(const bf16* __restrict__ A,
                                               const bf16* __restrict__ W,
                                               const float* __restrict__ bias,
                                               void* __restrict__ Cout,
                                               int M, int N, int K) {
    __shared__ __align__(16) bf16 lds_a[128 * 32];
    __shared__ __align__(16) bf16 lds_b[64 * 32];
    const int t = threadIdx.x;
    const int wave = t >> 6, lane = t & 63;
    const int m0 = blockIdx.x * 128, n0 = blockIdx.y * 64;
    const int wm = wave >> 1, wn = wave & 1;
    f32x4 acc[4][2] = {};
    const int arow = t >> 2;
    const int akg = (t & 3) * 8;
    const bf16* aptr0 = A + (size_t)(m0 + arow) * K + akg;
    const bf16* aptr1 = A + (size_t)(m0 + 64 + arow) * K + akg;
    const bf16* bptr = W + (size_t)(n0 + arow) * K + akg;
    bf16* la0 = lds_a + wave * 512;
    bf16* la1 = lds_a + 2048 + wave * 512;
    bf16* lb = lds_b + wave * 512;
    const int kq = (lane >> 4) * 8;
    const int fr = lane & 15;
    for (int kt = 0; kt < K; kt += 32) {
        __syncthreads();
        async16(la0, aptr0 + kt);
        async16(la1, aptr1 + kt);
        async16(lb, bptr + kt);
        __syncthreads();
        bf16x8 af[4], bfr[2];
#pragma unroll
        for (int mi = 0; mi < 4; ++mi)
            af[mi] = *(const bf16x8*)(lds_a + (wm * 64 + mi * 16 + fr) * 32 + kq);
#pragma unroll
        for (int ni = 0; ni < 2; ++ni)
            bfr[ni] = *(const bf16x8*)(lds_b + (wn * 32 + ni * 16 + fr) * 32 + kq);
#pragma unroll
        for (int mi = 0; mi < 4; ++mi)
#pragma unroll
            for (int ni = 0; ni < 2; ++ni)
                acc[mi][ni] = __builtin_amdgcn_mfma_f32_16x16x32_bf16(af[mi], bfr[ni], acc[mi][ni], 0, 0, 0);
    }
    const int rq4 = (lane >> 4) * 4;
#pragma unroll
    for (int mi = 0; mi < 4; ++mi) {
#pragma unroll
        for (int ni = 0; ni < 2; ++ni) {
            int gc = n0 + wn * 32 + ni * 16 + fr;
            float bv = bias ? bias[gc] : 0.0f;
            int grb = m0 + wm * 64 + mi * 16 + rq4;
#pragma unroll
            for (int j = 0; j < 4; ++j) {
                float v = acc[mi][ni][j] + bv;
                size_t idx = (size_t)(grb + j) * N + gc;
                if (EPI == 1) {
                    v = 0.5f * v * (1.0f + erff(v * 0.70710678118f));
                    ((bf16*)Cout)[idx] = __float2bfloat16(v);
                } else if (EPI == 2) {
                    float* Cf = (float*)Cout;
                    Cf[idx] = Cf[idx] + v;
                } else {
                    ((bf16*)Cout)[idx] = __float2bfloat16(v);
                }
            }
        }
    }
}

extern "C" void kernel_launch(void* const* d_in, const int* in_sizes, int n_in,
                              void* d_out, int out_size, void* d_ws, size_t ws_size,
                              hipStream_t stream) {
    const float* x      = (const float*)d_in[0];
    const float* n1g    = (const float*)d_in[1];
    const float* n1b    = (const float*)d_in[2];
    const float* rpbt   = (const float*)d_in[3];
    const float* qkv_v  = (const float*)d_in[4];
    const float* qkv_u  = (const float*)d_in[5];
    const float* qkv_b  = (const float*)d_in[6];
    const float* proj_v = (const float*)d_in[7];
    const float* proj_u = (const float*)d_in[8];
    const float* proj_b = (const float*)d_in[9];
    const float* n2g    = (const float*)d_in[10];
    const float* n2b    = (const float*)d_in[11];
    const float* fc1_v  = (const float*)d_in[12];
    const float* fc1_u  = (const float*)d_in[13];
    const float* fc1_b  = (const float*)d_in[14];
    const float* fc2_v  = (const float*)d_in[15];
    const float* fc2_u  = (const float*)d_in[16];
    const float* fc2_b  = (const float*)d_in[17];

    char* ws = (char*)d_ws;
    bf16* wb = (bf16*)ws;
    bf16* w_qkv_v  = wb;
    bf16* w_qkv_u  = wb + 73728;
    bf16* w_proj_v = wb + 294912;
    bf16* w_proj_u = wb + 368640;
    bf16* w_fc1_v  = wb + 442368;
    bf16* w_fc1_u  = wb + 516096;
    bf16* w_fc2_v  = wb + 811008;
    bf16* w_fc2_u  = wb + 1105920;
    size_t off = (size_t)4 << 20;
    bf16* R1 = (bf16*)(ws + off); off += (size_t)MROWS * 1536 * 2;   // qkv / proj / mlp-hidden
    bf16* R2 = (bf16*)(ws + off); off += (size_t)MROWS * 384 * 2;    // ywin / o / z
    bf16* R3 = (bf16*)(ws + off);                                    // t1/t2/t3/t4 (M x 192)
    float* out = (float*)d_out;

    auto cvt = [&](const float* s, bf16* d, int n) {
        f32_to_bf16_k<<<(n + 255) / 256, 256, 0, stream>>>(s, d, n);
    };
    cvt(qkv_v, w_qkv_v, 73728);
    cvt(qkv_u, w_qkv_u, 221184);
    cvt(proj_v, w_proj_v, 73728);
    cvt(proj_u, w_proj_u, 73728);
    cvt(fc1_v, w_fc1_v, 73728);
    cvt(fc1_u, w_fc1_u, 294912);
    cvt(fc2_v, w_fc2_v, 294912);
    cvt(fc2_u, w_fc2_u, 73728);

    ln1_window_k<<<MROWS / 4, 256, 0, stream>>>(x, n1g, n1b, R2);
    gemm_bt<0><<<dim3(784, 3), 256, 0, stream>>>(R2, w_qkv_v, nullptr, R3, MROWS, 192, 384);
    gemm_bt<0><<<dim3(784, 18), 256, 0, stream>>>(R3, w_qkv_u, qkv_b, R1, MROWS, 1152, 192);
    attn_k<<<2048 * 12, 256, 0, stream>>>(R1, rpbt, R2);
    gemm_bt<0><<<dim3(784, 3), 256, 0, stream>>>(R2, w_proj_v, nullptr, R3, MROWS, 192, 384);
    gemm_bt<0><<<dim3(784, 6), 256, 0, stream>>>(R3, w_proj_u, proj_b, R1, MROWS, 384, 192);
    resid_ln2_k<<<MROWS / 4, 256, 0, stream>>>(x, R1, n2g, n2b, out, R2);
    gemm_bt<0><<<dim3(784, 3), 256, 0, stream>>>(R2, w_fc1_v, nullptr, R3, MROWS, 192, 384);
    gemm_bt<1><<<dim3(784, 24), 256, 0, stream>>>(R3, w_fc1_u, fc1_b, R1, MROWS, 1536, 192);
    gemm_bt<0><<<dim3(784, 3), 256, 0, stream>>>(R1, w_fc2_v, nullptr, R3, MROWS, 192, 1536);
    gemm_bt<2><<<dim3(784, 6), 256, 0, stream>>>(R3, w_fc2_u, fc2_b, out, MROWS, 384, 192);
}

// Round 3
// 1239.580 us; speedup vs baseline: 1.2400x; 1.2400x over previous
//
#include <hip/hip_runtime.h>
#include <hip/hip_bf16.h>

using bf16 = __hip_bfloat16;
typedef __bf16 bf16x8 __attribute__((ext_vector_type(8)));
typedef float f32x4 __attribute__((ext_vector_type(4)));

#define MROWS 100352   // 2048 windows * 49 tokens = 32*3136

__device__ __forceinline__ void async16(void* l, const void* g) {
    void* gg = const_cast<void*>(g);
    __builtin_amdgcn_global_load_lds((__attribute__((address_space(1))) void*)gg,
                                     (__attribute__((address_space(3))) void*)l, 16, 0, 0);
}

__global__ __launch_bounds__(256) void f32_to_bf16_k(const float* __restrict__ s,
                                                     bf16* __restrict__ d, int n) {
    int i = blockIdx.x * 256 + threadIdx.x;
    if (i < n) d[i] = __float2bfloat16(s[i]);
}

// LN1 + cyclic shift(-3,-3) + window partition. One wave per output row.
__global__ __launch_bounds__(256) void ln1_window_k(const float* __restrict__ x,
                                                    const float* __restrict__ g,
                                                    const float* __restrict__ bta,
                                                    bf16* __restrict__ ywin) {
    int wrow = blockIdx.x * 4 + (threadIdx.x >> 6);
    int lane = threadIdx.x & 63;
    int tok = wrow % 49, win = wrow / 49;
    int i = tok / 7, j = tok % 7;
    int wwi = win & 7, whi = (win >> 3) & 7, bi = win >> 6;
    int hs = (whi * 7 + i + 3) % 56;
    int ws_ = (wwi * 7 + j + 3) % 56;
    const float* xr = x + ((size_t)bi * 3136 + (size_t)hs * 56 + ws_) * 384;
    float v[6]; float s = 0.f, s2 = 0.f;
#pragma unroll
    for (int u = 0; u < 6; ++u) { float t = xr[lane + 64 * u]; v[u] = t; s += t; s2 += t * t; }
#pragma unroll
    for (int d = 1; d < 64; d <<= 1) { s += __shfl_xor(s, d); s2 += __shfl_xor(s2, d); }
    float mean = s * (1.0f / 384.0f);
    float var = s2 * (1.0f / 384.0f) - mean * mean;
    float rstd = rsqrtf(var + 1e-5f);
    bf16* yr = ywin + (size_t)wrow * 384;
#pragma unroll
    for (int u = 0; u < 6; ++u) {
        int c = lane + 64 * u;
        yr[c] = __float2bfloat16((v[u] - mean) * rstd * g[c] + bta[c]);
    }
}

// residual add (window-reverse + roll(+3,+3)) + LN2. x2 -> d_out (fp32), z -> bf16
__global__ __launch_bounds__(256) void resid_ln2_k(const float* __restrict__ x,
                                                   const bf16* __restrict__ proj,
                                                   const float* __restrict__ g,
                                                   const float* __restrict__ bta,
                                                   float* __restrict__ x2,
                                                   bf16* __restrict__ z) {
    int row = blockIdx.x * 4 + (threadIdx.x >> 6);
    int lane = threadIdx.x & 63;
    int bi = row / 3136; int hw = row % 3136;
    int h = hw / 56, w = hw % 56;
    int h2 = (h + 53) % 56, w2 = (w + 53) % 56;
    int prow = ((bi * 8 + h2 / 7) * 8 + w2 / 7) * 49 + (h2 % 7) * 7 + (w2 % 7);
    const float* xr = x + (size_t)row * 384;
    const bf16* pr = proj + (size_t)prow * 384;
    float* x2r = x2 + (size_t)row * 384;
    float v[6]; float s = 0.f, s2 = 0.f;
#pragma unroll
    for (int u = 0; u < 6; ++u) {
        int c = lane + 64 * u;
        float t = xr[c] + __bfloat162float(pr[c]);
        v[u] = t; s += t; s2 += t * t;
        x2r[c] = t;
    }
#pragma unroll
    for (int d = 1; d < 64; d <<= 1) { s += __shfl_xor(s, d); s2 += __shfl_xor(s2, d); }
    float mean = s * (1.0f / 384.0f);
    float var = s2 * (1.0f / 384.0f) - mean * mean;
    float rstd = rsqrtf(var + 1e-5f);
    bf16* zr = z + (size_t)row * 384;
#pragma unroll
    for (int u = 0; u < 6; ++u) {
        int c = lane + 64 * u;
        zr[c] = __float2bfloat16((v[u] - mean) * rstd * g[c] + bta[c]);
    }
}

// MFMA windowed attention: one block per window; 4 waves x 3 rounds = 12 heads,
// one wave per head. All LDS wave-private -> zero barriers.
// P and V^T tiles: m-axis is the PV K-dim, padded to 64; stride 72 elem (144 B)
// keeps 16B alignment for ds_read_b128 and gives only 2-way (free) bank aliasing.
__global__ __launch_bounds__(256) void attn_mfma_k(const bf16* __restrict__ qkv,
                                                   const float* __restrict__ rpbt,
                                                   bf16* __restrict__ o) {
    __shared__ __align__(16) __bf16 vt_s[4][32 * 72];   // V^T  [d][m]
    __shared__ __align__(16) __bf16 p_s[4][64 * 72];    // P    [n][m]
    __shared__ float rpb_s[4][176];
    const int win = blockIdx.x;
    const int wave = threadIdx.x >> 6, lane = threadIdx.x & 63;
    const int lo = lane & 15, hi = lane >> 4;
    const int whi = (win >> 3) & 7, wwi = win & 7;
    const bool bH = (whi == 7), bW = (wwi == 7);
    __bf16* vt_w = vt_s[wave];
    __bf16* p_w = p_s[wave];
    float* rpb_w = rpb_s[wave];
    const bf16* wbase = qkv + (size_t)win * 49 * 1152;
    bf16x8 zf = {};

    for (int r = 0; r < 3; ++r) {
        const int h = r * 4 + wave;
        const bf16* qbase = wbase + h * 32;
        // rpb head slice -> LDS
        for (int idx = lane; idx < 169; idx += 64)
            rpb_w[idx] = rpbt[idx * 12 + h];
        // V -> LDS transposed (cols m>=49 zeroed)
#pragma unroll
        for (int it = 0; it < 4; ++it) {
            int idx = it * 64 + lane;
            int m = idx >> 2, dq = (idx & 3) * 8;
            bf16x8 v = (m < 49) ? *(const bf16x8*)(qbase + (size_t)m * 1152 + 768 + dq) : zf;
#pragma unroll
            for (int e = 0; e < 8; ++e)
                vt_w[(dq + e) * 72 + m] = v[e];
        }
        // Q/K fragments directly from global (K-dim = 32 = one MFMA k-step)
        bf16x8 aq[4], bk[4];
        const int kq = hi * 8;
#pragma unroll
        for (int ta = 0; ta < 4; ++ta) {
            int n = ta * 16 + lo;
            aq[ta] = (n < 49) ? *(const bf16x8*)(qbase + (size_t)n * 1152 + kq) : zf;
            bk[ta] = (n < 49) ? *(const bf16x8*)(qbase + (size_t)n * 1152 + 384 + kq) : zf;
        }
        // S = Q K^T : acc[ta][tb], row n = 16ta+4hi+j, col m = 16tb+lo
        f32x4 acc[4][4] = {};
#pragma unroll
        for (int ta = 0; ta < 4; ++ta)
#pragma unroll
            for (int tb = 0; tb < 4; ++tb)
                acc[ta][tb] = __builtin_amdgcn_mfma_f32_16x16x32_bf16(aq[ta], bk[tb], acc[ta][tb], 0, 0, 0);
        // scale + rpb + shift-mask (in place)
        int i2[4], j2[4], rm[4];
#pragma unroll
        for (int tb = 0; tb < 4; ++tb) {
            int m = tb * 16 + lo;
            int mm = m < 49 ? m : 0;
            i2[tb] = mm / 7; j2[tb] = mm % 7;
            rm[tb] = (bH ? (i2[tb] < 4 ? 1 : 2) : 0) * 3 + (bW ? (j2[tb] < 4 ? 1 : 2) : 0);
        }
#pragma unroll
        for (int ta = 0; ta < 4; ++ta) {
#pragma unroll
            for (int j = 0; j < 4; ++j) {
                int n = ta * 16 + hi * 4 + j;
                int nn = n < 49 ? n : 0;
                int i1 = nn / 7, j1 = nn % 7;
                int rn = (bH ? (i1 < 4 ? 1 : 2) : 0) * 3 + (bW ? (j1 < 4 ? 1 : 2) : 0);
#pragma unroll
                for (int tb = 0; tb < 4; ++tb) {
                    int m = tb * 16 + lo;
                    float v;
                    if (n < 49 && m < 49) {
                        v = acc[ta][tb][j] * 0.17677669529663687f
                            + rpb_w[(i1 - i2[tb] + 6) * 13 + (j1 - j2[tb] + 6)];
                        if (rn != rm[tb]) v -= 100.0f;
                    } else {
                        v = -1e30f;
                    }
                    acc[ta][tb][j] = v;
                }
            }
        }
        // wave-parallel softmax over m (in-lane over tb, shfl_xor over lane&15); P -> LDS bf16
#pragma unroll
        for (int ta = 0; ta < 4; ++ta) {
#pragma unroll
            for (int j = 0; j < 4; ++j) {
                float mx = fmaxf(fmaxf(acc[ta][0][j], acc[ta][1][j]),
                                 fmaxf(acc[ta][2][j], acc[ta][3][j]));
                mx = fmaxf(mx, __shfl_xor(mx, 1));
                mx = fmaxf(mx, __shfl_xor(mx, 2));
                mx = fmaxf(mx, __shfl_xor(mx, 4));
                mx = fmaxf(mx, __shfl_xor(mx, 8));
                float e0 = expf(acc[ta][0][j] - mx);
                float e1 = expf(acc[ta][1][j] - mx);
                float e2 = expf(acc[ta][2][j] - mx);
                float e3 = expf(acc[ta][3][j] - mx);
                float sm = e0 + e1 + e2 + e3;
                sm += __shfl_xor(sm, 1);
                sm += __shfl_xor(sm, 2);
                sm += __shfl_xor(sm, 4);
                sm += __shfl_xor(sm, 8);
                float inv = 1.0f / sm;
                int n = ta * 16 + hi * 4 + j;
                p_w[n * 72 + lo]      = (__bf16)(e0 * inv);
                p_w[n * 72 + 16 + lo] = (__bf16)(e1 * inv);
                p_w[n * 72 + 32 + lo] = (__bf16)(e2 * inv);
                p_w[n * 72 + 48 + lo] = (__bf16)(e3 * inv);
            }
        }
        // O = P V : A = P[n][m], B = V^T[d][m]
        f32x4 oacc[4][2] = {};
#pragma unroll
        for (int kb = 0; kb < 2; ++kb) {
            bf16x8 vb[2];
#pragma unroll
            for (int tb = 0; tb < 2; ++tb)
                vb[tb] = *(const bf16x8*)(vt_w + (tb * 16 + lo) * 72 + kb * 32 + hi * 8);
#pragma unroll
            for (int ta = 0; ta < 4; ++ta) {
                bf16x8 pa = *(const bf16x8*)(p_w + (ta * 16 + lo) * 72 + kb * 32 + hi * 8);
#pragma unroll
                for (int tb = 0; tb < 2; ++tb)
                    oacc[ta][tb] = __builtin_amdgcn_mfma_f32_16x16x32_bf16(pa, vb[tb], oacc[ta][tb], 0, 0, 0);
            }
        }
        bf16* obase = o + (size_t)win * 49 * 384 + h * 32;
#pragma unroll
        for (int ta = 0; ta < 4; ++ta) {
#pragma unroll
            for (int j = 0; j < 4; ++j) {
                int n = ta * 16 + hi * 4 + j;
                if (n < 49) {
#pragma unroll
                    for (int tb = 0; tb < 2; ++tb)
                        obase[(size_t)n * 384 + tb * 16 + lo] = __float2bfloat16(oacc[ta][tb][j]);
                }
            }
        }
    }
}

// C[M,N] = A[M,K] (bf16, row-major) @ W[N,K]^T (bf16, row-major) [+ bias][+ gelu | + inplace f32 add]
// EPI: 0 = store bf16 (+bias if given); 1 = bias+gelu -> bf16; 2 = bias + inplace add into f32 Cout
template <int EPI>
__global__ __launch_bounds__(256) void gemm_bt(const bf16* __restrict__ A,
                                               const bf16* __restrict__ W,
                                               const float* __restrict__ bias,
                                               void* __restrict__ Cout,
                                               int M, int N, int K) {
    __shared__ __align__(16) bf16 lds_a[128 * 32];
    __shared__ __align__(16) bf16 lds_b[64 * 32];
    const int t = threadIdx.x;
    const int wave = t >> 6, lane = t & 63;
    const int m0 = blockIdx.x * 128, n0 = blockIdx.y * 64;
    const int wm = wave >> 1, wn = wave & 1;
    f32x4 acc[4][2] = {};
    const int arow = t >> 2;
    const int akg = (t & 3) * 8;
    const bf16* aptr0 = A + (size_t)(m0 + arow) * K + akg;
    const bf16* aptr1 = A + (size_t)(m0 + 64 + arow) * K + akg;
    const bf16* bptr = W + (size_t)(n0 + arow) * K + akg;
    bf16* la0 = lds_a + wave * 512;
    bf16* la1 = lds_a + 2048 + wave * 512;
    bf16* lb = lds_b + wave * 512;
    const int kq = (lane >> 4) * 8;
    const int fr = lane & 15;
    for (int kt = 0; kt < K; kt += 32) {
        __syncthreads();
        async16(la0, aptr0 + kt);
        async16(la1, aptr1 + kt);
        async16(lb, bptr + kt);
        __syncthreads();
        bf16x8 af[4], bfr[2];
#pragma unroll
        for (int mi = 0; mi < 4; ++mi)
            af[mi] = *(const bf16x8*)(lds_a + (wm * 64 + mi * 16 + fr) * 32 + kq);
#pragma unroll
        for (int ni = 0; ni < 2; ++ni)
            bfr[ni] = *(const bf16x8*)(lds_b + (wn * 32 + ni * 16 + fr) * 32 + kq);
#pragma unroll
        for (int mi = 0; mi < 4; ++mi)
#pragma unroll
            for (int ni = 0; ni < 2; ++ni)
                acc[mi][ni] = __builtin_amdgcn_mfma_f32_16x16x32_bf16(af[mi], bfr[ni], acc[mi][ni], 0, 0, 0);
    }
    const int rq4 = (lane >> 4) * 4;
#pragma unroll
    for (int mi = 0; mi < 4; ++mi) {
#pragma unroll
        for (int ni = 0; ni < 2; ++ni) {
            int gc = n0 + wn * 32 + ni * 16 + fr;
            float bv = bias ? bias[gc] : 0.0f;
            int grb = m0 + wm * 64 + mi * 16 + rq4;
#pragma unroll
            for (int j = 0; j < 4; ++j) {
                float v = acc[mi][ni][j] + bv;
                size_t idx = (size_t)(grb + j) * N + gc;
                if (EPI == 1) {
                    v = 0.5f * v * (1.0f + erff(v * 0.70710678118f));
                    ((bf16*)Cout)[idx] = __float2bfloat16(v);
                } else if (EPI == 2) {
                    float* Cf = (float*)Cout;
                    Cf[idx] = Cf[idx] + v;
                } else {
                    ((bf16*)Cout)[idx] = __float2bfloat16(v);
                }
            }
        }
    }
}

extern "C" void kernel_launch(void* const* d_in, const int* in_sizes, int n_in,
                              void* d_out, int out_size, void* d_ws, size_t ws_size,
                              hipStream_t stream) {
    const float* x      = (const float*)d_in[0];
    const float* n1g    = (const float*)d_in[1];
    const float* n1b    = (const float*)d_in[2];
    const float* rpbt   = (const float*)d_in[3];
    const float* qkv_v  = (const float*)d_in[4];
    const float* qkv_u  = (const float*)d_in[5];
    const float* qkv_b  = (const float*)d_in[6];
    const float* proj_v = (const float*)d_in[7];
    const float* proj_u = (const float*)d_in[8];
    const float* proj_b = (const float*)d_in[9];
    const float* n2g    = (const float*)d_in[10];
    const float* n2b    = (const float*)d_in[11];
    const float* fc1_v  = (const float*)d_in[12];
    const float* fc1_u  = (const float*)d_in[13];
    const float* fc1_b  = (const float*)d_in[14];
    const float* fc2_v  = (const float*)d_in[15];
    const float* fc2_u  = (const float*)d_in[16];
    const float* fc2_b  = (const float*)d_in[17];

    char* ws = (char*)d_ws;
    bf16* wb = (bf16*)ws;
    bf16* w_qkv_v  = wb;
    bf16* w_qkv_u  = wb + 73728;
    bf16* w_proj_v = wb + 294912;
    bf16* w_proj_u = wb + 368640;
    bf16* w_fc1_v  = wb + 442368;
    bf16* w_fc1_u  = wb + 516096;
    bf16* w_fc2_v  = wb + 811008;
    bf16* w_fc2_u  = wb + 1105920;
    size_t off = (size_t)4 << 20;
    bf16* R1 = (bf16*)(ws + off); off += (size_t)MROWS * 1536 * 2;   // qkv / proj / mlp-hidden
    bf16* R2 = (bf16*)(ws + off); off += (size_t)MROWS * 384 * 2;    // ywin / o / z
    bf16* R3 = (bf16*)(ws + off);                                    // t1/t2/t3/t4 (M x 192)
    float* out = (float*)d_out;

    auto cvt = [&](const float* s, bf16* d, int n) {
        f32_to_bf16_k<<<(n + 255) / 256, 256, 0, stream>>>(s, d, n);
    };
    cvt(qkv_v, w_qkv_v, 73728);
    cvt(qkv_u, w_qkv_u, 221184);
    cvt(proj_v, w_proj_v, 73728);
    cvt(proj_u, w_proj_u, 73728);
    cvt(fc1_v, w_fc1_v, 73728);
    cvt(fc1_u, w_fc1_u, 294912);
    cvt(fc2_v, w_fc2_v, 294912);
    cvt(fc2_u, w_fc2_u, 73728);

    ln1_window_k<<<MROWS / 4, 256, 0, stream>>>(x, n1g, n1b, R2);
    gemm_bt<0><<<dim3(784, 3), 256, 0, stream>>>(R2, w_qkv_v, nullptr, R3, MROWS, 192, 384);
    gemm_bt<0><<<dim3(784, 18), 256, 0, stream>>>(R3, w_qkv_u, qkv_b, R1, MROWS, 1152, 192);
    attn_mfma_k<<<2048, 256, 0, stream>>>(R1, rpbt, R2);
    gemm_bt<0><<<dim3(784, 3), 256, 0, stream>>>(R2, w_proj_v, nullptr, R3, MROWS, 192, 384);
    gemm_bt<0><<<dim3(784, 6), 256, 0, stream>>>(R3, w_proj_u, proj_b, R1, MROWS, 384, 192);
    resid_ln2_k<<<MROWS / 4, 256, 0, stream>>>(x, R1, n2g, n2b, out, R2);
    gemm_bt<0><<<dim3(784, 3), 256, 0, stream>>>(R2, w_fc1_v, nullptr, R3, MROWS, 192, 384);
    gemm_bt<1><<<dim3(784, 24), 256, 0, stream>>>(R3, w_fc1_u, fc1_b, R1, MROWS, 1536, 192);
    gemm_bt<0><<<dim3(784, 3), 256, 0, stream>>>(R1, w_fc2_v, nullptr, R3, MROWS, 192, 1536);
    gemm_bt<2><<<dim3(784, 6), 256, 0, stream>>>(R3, w_fc2_u, fc2_b, out, MROWS, 384, 192);
}

// Round 4
// 1223.658 us; speedup vs baseline: 1.2561x; 1.0130x over previous
//
#include <hip/hip_runtime.h>
#include <hip/hip_bf16.h>

using bf16 = __hip_bfloat16;
typedef __bf16 bf16x8 __attribute__((ext_vector_type(8)));
typedef float f32x4 __attribute__((ext_vector_type(4)));

#define MROWS 100352   // 2048 windows * 49 tokens = 32*3136

__device__ __forceinline__ void async16(void* l, const void* g) {
    void* gg = const_cast<void*>(g);
    __builtin_amdgcn_global_load_lds((__attribute__((address_space(1))) void*)gg,
                                     (__attribute__((address_space(3))) void*)l, 16, 0, 0);
}

struct Cvt8 { const float* s[8]; bf16* d[8]; int n[8]; };

__global__ __launch_bounds__(256) void cvt8_k(Cvt8 c) {
    int seg = blockIdx.y;
    int i4 = (blockIdx.x * 256 + threadIdx.x) * 4;
    if (i4 < c.n[seg]) {
        float4 v = *(const float4*)(c.s[seg] + i4);
        bf16* d = c.d[seg] + i4;
        d[0] = __float2bfloat16(v.x);
        d[1] = __float2bfloat16(v.y);
        d[2] = __float2bfloat16(v.z);
        d[3] = __float2bfloat16(v.w);
    }
}

// LN1 + cyclic shift(-3,-3) + window partition. One wave per output row.
__global__ __launch_bounds__(256) void ln1_window_k(const float* __restrict__ x,
                                                    const float* __restrict__ g,
                                                    const float* __restrict__ bta,
                                                    bf16* __restrict__ ywin) {
    int wrow = blockIdx.x * 4 + (threadIdx.x >> 6);
    int lane = threadIdx.x & 63;
    int tok = wrow % 49, win = wrow / 49;
    int i = tok / 7, j = tok % 7;
    int wwi = win & 7, whi = (win >> 3) & 7, bi = win >> 6;
    int hs = (whi * 7 + i + 3) % 56;
    int ws_ = (wwi * 7 + j + 3) % 56;
    const float* xr = x + ((size_t)bi * 3136 + (size_t)hs * 56 + ws_) * 384;
    float v[6]; float s = 0.f, s2 = 0.f;
#pragma unroll
    for (int u = 0; u < 6; ++u) { float t = xr[lane + 64 * u]; v[u] = t; s += t; s2 += t * t; }
#pragma unroll
    for (int d = 1; d < 64; d <<= 1) { s += __shfl_xor(s, d); s2 += __shfl_xor(s2, d); }
    float mean = s * (1.0f / 384.0f);
    float var = s2 * (1.0f / 384.0f) - mean * mean;
    float rstd = rsqrtf(var + 1e-5f);
    bf16* yr = ywin + (size_t)wrow * 384;
#pragma unroll
    for (int u = 0; u < 6; ++u) {
        int c = lane + 64 * u;
        yr[c] = __float2bfloat16((v[u] - mean) * rstd * g[c] + bta[c]);
    }
}

// residual add (window-reverse + roll(+3,+3)) + LN2. x2 -> d_out (fp32), z -> bf16
__global__ __launch_bounds__(256) void resid_ln2_k(const float* __restrict__ x,
                                                   const bf16* __restrict__ proj,
                                                   const float* __restrict__ g,
                                                   const float* __restrict__ bta,
                                                   float* __restrict__ x2,
                                                   bf16* __restrict__ z) {
    int row = blockIdx.x * 4 + (threadIdx.x >> 6);
    int lane = threadIdx.x & 63;
    int bi = row / 3136; int hw = row % 3136;
    int h = hw / 56, w = hw % 56;
    int h2 = (h + 53) % 56, w2 = (w + 53) % 56;
    int prow = ((bi * 8 + h2 / 7) * 8 + w2 / 7) * 49 + (h2 % 7) * 7 + (w2 % 7);
    const float* xr = x + (size_t)row * 384;
    const bf16* pr = proj + (size_t)prow * 384;
    float* x2r = x2 + (size_t)row * 384;
    float v[6]; float s = 0.f, s2 = 0.f;
#pragma unroll
    for (int u = 0; u < 6; ++u) {
        int c = lane + 64 * u;
        float t = xr[c] + __bfloat162float(pr[c]);
        v[u] = t; s += t; s2 += t * t;
        x2r[c] = t;
    }
#pragma unroll
    for (int d = 1; d < 64; d <<= 1) { s += __shfl_xor(s, d); s2 += __shfl_xor(s2, d); }
    float mean = s * (1.0f / 384.0f);
    float var = s2 * (1.0f / 384.0f) - mean * mean;
    float rstd = rsqrtf(var + 1e-5f);
    bf16* zr = z + (size_t)row * 384;
#pragma unroll
    for (int u = 0; u < 6; ++u) {
        int c = lane + 64 * u;
        zr[c] = __float2bfloat16((v[u] - mean) * rstd * g[c] + bta[c]);
    }
}

// MFMA windowed attention: one block per window; 4 waves x 3 rounds = 12 heads.
// LDS trimmed to 44.9 KB -> 3 blocks/CU (VGPR 156 also allows 3 waves/SIMD):
//   - PV runs in two 32-row halves so the P tile is [32][72] per wave
//   - rpb table (169x12 f32) loaded cooperatively once per block
__global__ __launch_bounds__(256) void attn_mfma_k(const bf16* __restrict__ qkv,
                                                   const float* __restrict__ rpbt,
                                                   bf16* __restrict__ o) {
    __shared__ __align__(16) __bf16 vt_s[4][32 * 72];   // V^T  [d][m], m padded to 64
    __shared__ __align__(16) __bf16 p_s[4][32 * 72];    // P half [n_loc][m]
    __shared__ float rpb_sh[2028];                      // [ridx][h]
    const int win = blockIdx.x;
    const int wave = threadIdx.x >> 6, lane = threadIdx.x & 63;
    const int lo = lane & 15, hi = lane >> 4;
    const int whi = (win >> 3) & 7, wwi = win & 7;
    const bool bH = (whi == 7), bW = (wwi == 7);
    __bf16* vt_w = vt_s[wave];
    __bf16* p_w = p_s[wave];
    const bf16* wbase = qkv + (size_t)win * 49 * 1152;
    bf16x8 zf = {};

    for (int idx = threadIdx.x; idx < 2028; idx += 256) rpb_sh[idx] = rpbt[idx];
    __syncthreads();

    for (int r = 0; r < 3; ++r) {
        const int h = r * 4 + wave;
        const bf16* qbase = wbase + h * 32;
        // V -> LDS transposed (cols m>=49 zeroed)
#pragma unroll
        for (int it = 0; it < 4; ++it) {
            int idx = it * 64 + lane;
            int m = idx >> 2, dq = (idx & 3) * 8;
            bf16x8 v = (m < 49) ? *(const bf16x8*)(qbase + (size_t)m * 1152 + 768 + dq) : zf;
#pragma unroll
            for (int e = 0; e < 8; ++e)
                vt_w[(dq + e) * 72 + m] = v[e];
        }
        // Q/K fragments directly from global (K-dim = 32 = one MFMA k-step)
        bf16x8 aq[4], bk[4];
        const int kq = hi * 8;
#pragma unroll
        for (int ta = 0; ta < 4; ++ta) {
            int n = ta * 16 + lo;
            aq[ta] = (n < 49) ? *(const bf16x8*)(qbase + (size_t)n * 1152 + kq) : zf;
            bk[ta] = (n < 49) ? *(const bf16x8*)(qbase + (size_t)n * 1152 + 384 + kq) : zf;
        }
        // S = Q K^T : acc[ta][tb], row n = 16ta+4hi+j, col m = 16tb+lo
        f32x4 acc[4][4] = {};
#pragma unroll
        for (int ta = 0; ta < 4; ++ta)
#pragma unroll
            for (int tb = 0; tb < 4; ++tb)
                acc[ta][tb] = __builtin_amdgcn_mfma_f32_16x16x32_bf16(aq[ta], bk[tb], acc[ta][tb], 0, 0, 0);
        // scale + rpb + shift-mask (in place)
        int i2[4], j2[4], rm[4];
#pragma unroll
        for (int tb = 0; tb < 4; ++tb) {
            int m = tb * 16 + lo;
            int mm = m < 49 ? m : 0;
            i2[tb] = mm / 7; j2[tb] = mm % 7;
            rm[tb] = (bH ? (i2[tb] < 4 ? 1 : 2) : 0) * 3 + (bW ? (j2[tb] < 4 ? 1 : 2) : 0);
        }
#pragma unroll
        for (int ta = 0; ta < 4; ++ta) {
#pragma unroll
            for (int j = 0; j < 4; ++j) {
                int n = ta * 16 + hi * 4 + j;
                int nn = n < 49 ? n : 0;
                int i1 = nn / 7, j1 = nn % 7;
                int rn = (bH ? (i1 < 4 ? 1 : 2) : 0) * 3 + (bW ? (j1 < 4 ? 1 : 2) : 0);
#pragma unroll
                for (int tb = 0; tb < 4; ++tb) {
                    int m = tb * 16 + lo;
                    float v;
                    if (n < 49 && m < 49) {
                        v = acc[ta][tb][j] * 0.17677669529663687f
                            + rpb_sh[((i1 - i2[tb] + 6) * 13 + (j1 - j2[tb] + 6)) * 12 + h];
                        if (rn != rm[tb]) v -= 100.0f;
                    } else {
                        v = -1e30f;
                    }
                    acc[ta][tb][j] = v;
                }
            }
        }
        // V^T fragments (B-operand) hoisted once
        bf16x8 vb[2][2];
#pragma unroll
        for (int kb = 0; kb < 2; ++kb)
#pragma unroll
            for (int tb = 0; tb < 2; ++tb)
                vb[kb][tb] = *(const bf16x8*)(vt_w + (tb * 16 + lo) * 72 + kb * 32 + hi * 8);

        f32x4 oacc[4][2] = {};
        // two halves of 32 rows: softmax -> P half tile -> PV
#pragma unroll
        for (int half = 0; half < 2; ++half) {
#pragma unroll
            for (int tq = 0; tq < 2; ++tq) {
                int ta = half * 2 + tq;
#pragma unroll
                for (int j = 0; j < 4; ++j) {
                    float mx = fmaxf(fmaxf(acc[ta][0][j], acc[ta][1][j]),
                                     fmaxf(acc[ta][2][j], acc[ta][3][j]));
                    mx = fmaxf(mx, __shfl_xor(mx, 1));
                    mx = fmaxf(mx, __shfl_xor(mx, 2));
                    mx = fmaxf(mx, __shfl_xor(mx, 4));
                    mx = fmaxf(mx, __shfl_xor(mx, 8));
                    float e0 = expf(acc[ta][0][j] - mx);
                    float e1 = expf(acc[ta][1][j] - mx);
                    float e2 = expf(acc[ta][2][j] - mx);
                    float e3 = expf(acc[ta][3][j] - mx);
                    float sm = e0 + e1 + e2 + e3;
                    sm += __shfl_xor(sm, 1);
                    sm += __shfl_xor(sm, 2);
                    sm += __shfl_xor(sm, 4);
                    sm += __shfl_xor(sm, 8);
                    float inv = 1.0f / sm;
                    int nl = tq * 16 + hi * 4 + j;
                    p_w[nl * 72 + lo]      = (__bf16)(e0 * inv);
                    p_w[nl * 72 + 16 + lo] = (__bf16)(e1 * inv);
                    p_w[nl * 72 + 32 + lo] = (__bf16)(e2 * inv);
                    p_w[nl * 72 + 48 + lo] = (__bf16)(e3 * inv);
                }
            }
#pragma unroll
            for (int kb = 0; kb < 2; ++kb) {
#pragma unroll
                for (int tq = 0; tq < 2; ++tq) {
                    bf16x8 pa = *(const bf16x8*)(p_w + (tq * 16 + lo) * 72 + kb * 32 + hi * 8);
#pragma unroll
                    for (int tb = 0; tb < 2; ++tb)
                        oacc[half * 2 + tq][tb] =
                            __builtin_amdgcn_mfma_f32_16x16x32_bf16(pa, vb[kb][tb], oacc[half * 2 + tq][tb], 0, 0, 0);
                }
            }
        }
        bf16* obase = o + (size_t)win * 49 * 384 + h * 32;
#pragma unroll
        for (int ta = 0; ta < 4; ++ta) {
#pragma unroll
            for (int j = 0; j < 4; ++j) {
                int n = ta * 16 + hi * 4 + j;
                if (n < 49) {
#pragma unroll
                    for (int tb = 0; tb < 2; ++tb)
                        obase[(size_t)n * 384 + tb * 16 + lo] = __float2bfloat16(oacc[ta][tb][j]);
                }
            }
        }
    }
}

// C[M,N] = A[M,K] (bf16, row-major) @ W[N,K]^T (bf16, row-major) [+ bias][+ gelu | + inplace f32 add]
// 2-phase double-buffered: issue next tile's global_load_lds BEFORE computing
// the current tile; single __syncthreads per K-step (implicit vmcnt(0) drain).
template <int EPI>
__global__ __launch_bounds__(256) void gemm_bt(const bf16* __restrict__ A,
                                               const bf16* __restrict__ W,
                                               const float* __restrict__ bias,
                                               void* __restrict__ Cout,
                                               int M, int N, int K) {
    __shared__ __align__(16) bf16 lds_a[2][128 * 32];
    __shared__ __align__(16) bf16 lds_b[2][64 * 32];
    const int t = threadIdx.x;
    const int wave = t >> 6, lane = t & 63;
    const int m0 = blockIdx.x * 128, n0 = blockIdx.y * 64;
    const int wm = wave >> 1, wn = wave & 1;
    f32x4 acc[4][2] = {};
    const int arow = t >> 2;
    const int akg = (t & 3) * 8;
    const bf16* aptr0 = A + (size_t)(m0 + arow) * K + akg;
    const bf16* aptr1 = A + (size_t)(m0 + 64 + arow) * K + akg;
    const bf16* bptr = W + (size_t)(n0 + arow) * K + akg;
    const int kq = (lane >> 4) * 8;
    const int fr = lane & 15;
    // prologue: stage kt=0 into buf 0
    async16(&lds_a[0][wave * 512], aptr0);
    async16(&lds_a[0][2048 + wave * 512], aptr1);
    async16(&lds_b[0][wave * 512], bptr);
    __syncthreads();
    int buf = 0;
    for (int kt = 0; kt < K; kt += 32) {
        if (kt + 32 < K) {
            async16(&lds_a[buf ^ 1][wave * 512], aptr0 + kt + 32);
            async16(&lds_a[buf ^ 1][2048 + wave * 512], aptr1 + kt + 32);
            async16(&lds_b[buf ^ 1][wave * 512], bptr + kt + 32);
        }
        bf16x8 af[4], bfr[2];
#pragma unroll
        for (int mi = 0; mi < 4; ++mi)
            af[mi] = *(const bf16x8*)(&lds_a[buf][(wm * 64 + mi * 16 + fr) * 32 + kq]);
#pragma unroll
        for (int ni = 0; ni < 2; ++ni)
            bfr[ni] = *(const bf16x8*)(&lds_b[buf][(wn * 32 + ni * 16 + fr) * 32 + kq]);
#pragma unroll
        for (int mi = 0; mi < 4; ++mi)
#pragma unroll
            for (int ni = 0; ni < 2; ++ni)
                acc[mi][ni] = __builtin_amdgcn_mfma_f32_16x16x32_bf16(af[mi], bfr[ni], acc[mi][ni], 0, 0, 0);
        __syncthreads();
        buf ^= 1;
    }
    const int rq4 = (lane >> 4) * 4;
#pragma unroll
    for (int mi = 0; mi < 4; ++mi) {
#pragma unroll
        for (int ni = 0; ni < 2; ++ni) {
            int gc = n0 + wn * 32 + ni * 16 + fr;
            float bv = bias ? bias[gc] : 0.0f;
            int grb = m0 + wm * 64 + mi * 16 + rq4;
#pragma unroll
            for (int j = 0; j < 4; ++j) {
                float v = acc[mi][ni][j] + bv;
                size_t idx = (size_t)(grb + j) * N + gc;
                if (EPI == 1) {
                    v = 0.5f * v * (1.0f + erff(v * 0.70710678118f));
                    ((bf16*)Cout)[idx] = __float2bfloat16(v);
                } else if (EPI == 2) {
                    float* Cf = (float*)Cout;
                    Cf[idx] = Cf[idx] + v;
                } else {
                    ((bf16*)Cout)[idx] = __float2bfloat16(v);
                }
            }
        }
    }
}

extern "C" void kernel_launch(void* const* d_in, const int* in_sizes, int n_in,
                              void* d_out, int out_size, void* d_ws, size_t ws_size,
                              hipStream_t stream) {
    const float* x      = (const float*)d_in[0];
    const float* n1g    = (const float*)d_in[1];
    const float* n1b    = (const float*)d_in[2];
    const float* rpbt   = (const float*)d_in[3];
    const float* qkv_v  = (const float*)d_in[4];
    const float* qkv_u  = (const float*)d_in[5];
    const float* qkv_b  = (const float*)d_in[6];
    const float* proj_v = (const float*)d_in[7];
    const float* proj_u = (const float*)d_in[8];
    const float* proj_b = (const float*)d_in[9];
    const float* n2g    = (const float*)d_in[10];
    const float* n2b    = (const float*)d_in[11];
    const float* fc1_v  = (const float*)d_in[12];
    const float* fc1_u  = (const float*)d_in[13];
    const float* fc1_b  = (const float*)d_in[14];
    const float* fc2_v  = (const float*)d_in[15];
    const float* fc2_u  = (const float*)d_in[16];
    const float* fc2_b  = (const float*)d_in[17];

    char* ws = (char*)d_ws;
    bf16* wb = (bf16*)ws;
    bf16* w_qkv_v  = wb;
    bf16* w_qkv_u  = wb + 73728;
    bf16* w_proj_v = wb + 294912;
    bf16* w_proj_u = wb + 368640;
    bf16* w_fc1_v  = wb + 442368;
    bf16* w_fc1_u  = wb + 516096;
    bf16* w_fc2_v  = wb + 811008;
    bf16* w_fc2_u  = wb + 1105920;
    size_t off = (size_t)4 << 20;
    bf16* R1 = (bf16*)(ws + off); off += (size_t)MROWS * 1536 * 2;   // qkv / proj / mlp-hidden
    bf16* R2 = (bf16*)(ws + off); off += (size_t)MROWS * 384 * 2;    // ywin / o / z
    bf16* R3 = (bf16*)(ws + off);                                    // t1/t2/t3/t4 (M x 192)
    float* out = (float*)d_out;

    Cvt8 c;
    c.s[0] = qkv_v;  c.d[0] = w_qkv_v;  c.n[0] = 73728;
    c.s[1] = qkv_u;  c.d[1] = w_qkv_u;  c.n[1] = 221184;
    c.s[2] = proj_v; c.d[2] = w_proj_v; c.n[2] = 73728;
    c.s[3] = proj_u; c.d[3] = w_proj_u; c.n[3] = 73728;
    c.s[4] = fc1_v;  c.d[4] = w_fc1_v;  c.n[4] = 73728;
    c.s[5] = fc1_u;  c.d[5] = w_fc1_u;  c.n[5] = 294912;
    c.s[6] = fc2_v;  c.d[6] = w_fc2_v;  c.n[6] = 294912;
    c.s[7] = fc2_u;  c.d[7] = w_fc2_u;  c.n[7] = 73728;
    cvt8_k<<<dim3(288, 8), 256, 0, stream>>>(c);

    ln1_window_k<<<MROWS / 4, 256, 0, stream>>>(x, n1g, n1b, R2);
    gemm_bt<0><<<dim3(784, 3), 256, 0, stream>>>(R2, w_qkv_v, nullptr, R3, MROWS, 192, 384);
    gemm_bt<0><<<dim3(784, 18), 256, 0, stream>>>(R3, w_qkv_u, qkv_b, R1, MROWS, 1152, 192);
    attn_mfma_k<<<2048, 256, 0, stream>>>(R1, rpbt, R2);
    gemm_bt<0><<<dim3(784, 3), 256, 0, stream>>>(R2, w_proj_v, nullptr, R3, MROWS, 192, 384);
    gemm_bt<0><<<dim3(784, 6), 256, 0, stream>>>(R3, w_proj_u, proj_b, R1, MROWS, 384, 192);
    resid_ln2_k<<<MROWS / 4, 256, 0, stream>>>(x, R1, n2g, n2b, out, R2);
    gemm_bt<0><<<dim3(784, 3), 256, 0, stream>>>(R2, w_fc1_v, nullptr, R3, MROWS, 192, 384);
    gemm_bt<1><<<dim3(784, 24), 256, 0, stream>>>(R3, w_fc1_u, fc1_b, R1, MROWS, 1536, 192);
    gemm_bt<0><<<dim3(784, 3), 256, 0, stream>>>(R1, w_fc2_v, nullptr, R3, MROWS, 192, 1536);
    gemm_bt<2><<<dim3(784, 6), 256, 0, stream>>>(R3, w_fc2_u, fc2_b, out, MROWS, 384, 192);
}

// Round 5
// 1170.997 us; speedup vs baseline: 1.3126x; 1.0450x over previous
//
#include <hip/hip_runtime.h>
#include <hip/hip_bf16.h>

using bf16 = __hip_bfloat16;
typedef __bf16 bf16x8 __attribute__((ext_vector_type(8)));
typedef float f32x4 __attribute__((ext_vector_type(4)));

#define MROWS 100352   // 2048 windows * 49 tokens = 32*3136

__device__ __forceinline__ void async16(void* l, const void* g) {
    void* gg = const_cast<void*>(g);
    __builtin_amdgcn_global_load_lds((__attribute__((address_space(1))) void*)gg,
                                     (__attribute__((address_space(3))) void*)l, 16, 0, 0);
}

struct Cvt8 { const float* s[8]; bf16* d[8]; int n[8]; };

__global__ __launch_bounds__(256) void cvt8_k(Cvt8 c) {
    int seg = blockIdx.y;
    int i4 = (blockIdx.x * 256 + threadIdx.x) * 4;
    if (i4 < c.n[seg]) {
        float4 v = *(const float4*)(c.s[seg] + i4);
        bf16* d = c.d[seg] + i4;
        d[0] = __float2bfloat16(v.x);
        d[1] = __float2bfloat16(v.y);
        d[2] = __float2bfloat16(v.z);
        d[3] = __float2bfloat16(v.w);
    }
}

// LN1 + cyclic shift(-3,-3) + window partition. One wave per output row.
__global__ __launch_bounds__(256) void ln1_window_k(const float* __restrict__ x,
                                                    const float* __restrict__ g,
                                                    const float* __restrict__ bta,
                                                    bf16* __restrict__ ywin) {
    int wrow = blockIdx.x * 4 + (threadIdx.x >> 6);
    int lane = threadIdx.x & 63;
    int tok = wrow % 49, win = wrow / 49;
    int i = tok / 7, j = tok % 7;
    int wwi = win & 7, whi = (win >> 3) & 7, bi = win >> 6;
    int hs = (whi * 7 + i + 3) % 56;
    int ws_ = (wwi * 7 + j + 3) % 56;
    const float* xr = x + ((size_t)bi * 3136 + (size_t)hs * 56 + ws_) * 384;
    float v[6]; float s = 0.f, s2 = 0.f;
#pragma unroll
    for (int u = 0; u < 6; ++u) { float t = xr[lane + 64 * u]; v[u] = t; s += t; s2 += t * t; }
#pragma unroll
    for (int d = 1; d < 64; d <<= 1) { s += __shfl_xor(s, d); s2 += __shfl_xor(s2, d); }
    float mean = s * (1.0f / 384.0f);
    float var = s2 * (1.0f / 384.0f) - mean * mean;
    float rstd = rsqrtf(var + 1e-5f);
    bf16* yr = ywin + (size_t)wrow * 384;
#pragma unroll
    for (int u = 0; u < 6; ++u) {
        int c = lane + 64 * u;
        yr[c] = __float2bfloat16((v[u] - mean) * rstd * g[c] + bta[c]);
    }
}

// residual add (window-reverse + roll(+3,+3)) + LN2. x2 -> d_out (fp32), z -> bf16
__global__ __launch_bounds__(256) void resid_ln2_k(const float* __restrict__ x,
                                                   const bf16* __restrict__ proj,
                                                   const float* __restrict__ g,
                                                   const float* __restrict__ bta,
                                                   float* __restrict__ x2,
                                                   bf16* __restrict__ z) {
    int row = blockIdx.x * 4 + (threadIdx.x >> 6);
    int lane = threadIdx.x & 63;
    int bi = row / 3136; int hw = row % 3136;
    int h = hw / 56, w = hw % 56;
    int h2 = (h + 53) % 56, w2 = (w + 53) % 56;
    int prow = ((bi * 8 + h2 / 7) * 8 + w2 / 7) * 49 + (h2 % 7) * 7 + (w2 % 7);
    const float* xr = x + (size_t)row * 384;
    const bf16* pr = proj + (size_t)prow * 384;
    float* x2r = x2 + (size_t)row * 384;
    float v[6]; float s = 0.f, s2 = 0.f;
#pragma unroll
    for (int u = 0; u < 6; ++u) {
        int c = lane + 64 * u;
        float t = xr[c] + __bfloat162float(pr[c]);
        v[u] = t; s += t; s2 += t * t;
        x2r[c] = t;
    }
#pragma unroll
    for (int d = 1; d < 64; d <<= 1) { s += __shfl_xor(s, d); s2 += __shfl_xor(s2, d); }
    float mean = s * (1.0f / 384.0f);
    float var = s2 * (1.0f / 384.0f) - mean * mean;
    float rstd = rsqrtf(var + 1e-5f);
    bf16* zr = z + (size_t)row * 384;
#pragma unroll
    for (int u = 0; u < 6; ++u) {
        int c = lane + 64 * u;
        zr[c] = __float2bfloat16((v[u] - mean) * rstd * g[c] + bta[c]);
    }
}

// MFMA windowed attention: grid (2048 windows, 3 head-groups); 4 waves,
// one wave per head; one round per block. All LDS wave-private after the
// initial rpb stage -> one barrier per block.
__global__ __launch_bounds__(256) void attn_mfma_k(const bf16* __restrict__ qkv,
                                                   const float* __restrict__ rpbt,
                                                   bf16* __restrict__ o) {
    __shared__ __align__(16) __bf16 vt_s[4][32 * 72];   // V^T  [d][m], m padded to 64
    __shared__ __align__(16) __bf16 p_s[4][32 * 72];    // P half [n_loc][m]
    __shared__ float rpb_sh[676];                       // [ridx][4 heads of this group]
    const int win = blockIdx.x;
    const int r = blockIdx.y;
    const int wave = threadIdx.x >> 6, lane = threadIdx.x & 63;
    const int lo = lane & 15, hi = lane >> 4;
    const int whi = (win >> 3) & 7, wwi = win & 7;
    const bool bH = (whi == 7), bW = (wwi == 7);
    const bool boundary = bH || bW;
    __bf16* vt_w = vt_s[wave];
    __bf16* p_w = p_s[wave];
    const int h = r * 4 + wave;
    const bf16* qbase = qkv + (size_t)win * 49 * 1152 + h * 32;
    bf16x8 zf = {};

    for (int idx = threadIdx.x; idx < 676; idx += 256)
        rpb_sh[idx] = rpbt[(idx >> 2) * 12 + r * 4 + (idx & 3)];
    __syncthreads();

    // V -> LDS transposed; lane handles column m (write banks 2-way = free)
    {
        int m = lane;
        bf16x8 vrow[4];
#pragma unroll
        for (int d8 = 0; d8 < 4; ++d8)
            vrow[d8] = (m < 49) ? *(const bf16x8*)(qbase + (size_t)m * 1152 + 768 + d8 * 8) : zf;
#pragma unroll
        for (int d8 = 0; d8 < 4; ++d8)
#pragma unroll
            for (int e = 0; e < 8; ++e)
                vt_w[(d8 * 8 + e) * 72 + m] = vrow[d8][e];
    }
    // Q/K fragments directly from global (K-dim = 32 = one MFMA k-step)
    bf16x8 aq[4], bk[4];
    const int kq = hi * 8;
#pragma unroll
    for (int ta = 0; ta < 4; ++ta) {
        int n = ta * 16 + lo;
        aq[ta] = (n < 49) ? *(const bf16x8*)(qbase + (size_t)n * 1152 + kq) : zf;
        bk[ta] = (n < 49) ? *(const bf16x8*)(qbase + (size_t)n * 1152 + 384 + kq) : zf;
    }
    // S = Q K^T : acc[ta][tb], row n = 16ta+4hi+j, col m = 16tb+lo
    f32x4 acc[4][4] = {};
#pragma unroll
    for (int ta = 0; ta < 4; ++ta)
#pragma unroll
        for (int tb = 0; tb < 4; ++tb)
            acc[ta][tb] = __builtin_amdgcn_mfma_f32_16x16x32_bf16(aq[ta], bk[tb], acc[ta][tb], 0, 0, 0);
    // scale + rpb + shift-mask (in place)
    int i2[4], j2[4], rm[4];
#pragma unroll
    for (int tb = 0; tb < 4; ++tb) {
        int m = tb * 16 + lo;
        int mm = m < 49 ? m : 0;
        i2[tb] = mm / 7; j2[tb] = mm % 7;
        rm[tb] = (bH ? (i2[tb] < 4 ? 1 : 2) : 0) * 3 + (bW ? (j2[tb] < 4 ? 1 : 2) : 0);
    }
#pragma unroll
    for (int ta = 0; ta < 4; ++ta) {
#pragma unroll
        for (int j = 0; j < 4; ++j) {
            int n = ta * 16 + hi * 4 + j;
            int nn = n < 49 ? n : 0;
            int i1 = nn / 7, j1 = nn % 7;
            int rn = (bH ? (i1 < 4 ? 1 : 2) : 0) * 3 + (bW ? (j1 < 4 ? 1 : 2) : 0);
#pragma unroll
            for (int tb = 0; tb < 4; ++tb) {
                int m = tb * 16 + lo;
                float v;
                if (n < 49 && m < 49) {
                    v = acc[ta][tb][j] * 0.17677669529663687f
                        + rpb_sh[((i1 - i2[tb] + 6) * 13 + (j1 - j2[tb] + 6)) * 4 + wave];
                    if (boundary && rn != rm[tb]) v -= 100.0f;
                } else {
                    v = -1e30f;
                }
                acc[ta][tb][j] = v;
            }
        }
    }
    // V^T fragments (B-operand) hoisted once
    bf16x8 vb[2][2];
#pragma unroll
    for (int kb = 0; kb < 2; ++kb)
#pragma unroll
        for (int tb = 0; tb < 2; ++tb)
            vb[kb][tb] = *(const bf16x8*)(vt_w + (tb * 16 + lo) * 72 + kb * 32 + hi * 8);

    f32x4 oacc[4][2] = {};
    // two halves of 32 rows: softmax -> P half tile -> PV
#pragma unroll
    for (int half = 0; half < 2; ++half) {
#pragma unroll
        for (int tq = 0; tq < 2; ++tq) {
            int ta = half * 2 + tq;
#pragma unroll
            for (int j = 0; j < 4; ++j) {
                float mx = fmaxf(fmaxf(acc[ta][0][j], acc[ta][1][j]),
                                 fmaxf(acc[ta][2][j], acc[ta][3][j]));
                mx = fmaxf(mx, __shfl_xor(mx, 1));
                mx = fmaxf(mx, __shfl_xor(mx, 2));
                mx = fmaxf(mx, __shfl_xor(mx, 4));
                mx = fmaxf(mx, __shfl_xor(mx, 8));
                float e0 = __expf(acc[ta][0][j] - mx);
                float e1 = __expf(acc[ta][1][j] - mx);
                float e2 = __expf(acc[ta][2][j] - mx);
                float e3 = __expf(acc[ta][3][j] - mx);
                float sm = e0 + e1 + e2 + e3;
                sm += __shfl_xor(sm, 1);
                sm += __shfl_xor(sm, 2);
                sm += __shfl_xor(sm, 4);
                sm += __shfl_xor(sm, 8);
                float inv = 1.0f / sm;
                int nl = tq * 16 + hi * 4 + j;
                p_w[nl * 72 + lo]      = (__bf16)(e0 * inv);
                p_w[nl * 72 + 16 + lo] = (__bf16)(e1 * inv);
                p_w[nl * 72 + 32 + lo] = (__bf16)(e2 * inv);
                p_w[nl * 72 + 48 + lo] = (__bf16)(e3 * inv);
            }
        }
#pragma unroll
        for (int kb = 0; kb < 2; ++kb) {
#pragma unroll
            for (int tq = 0; tq < 2; ++tq) {
                bf16x8 pa = *(const bf16x8*)(p_w + (tq * 16 + lo) * 72 + kb * 32 + hi * 8);
#pragma unroll
                for (int tb = 0; tb < 2; ++tb)
                    oacc[half * 2 + tq][tb] =
                        __builtin_amdgcn_mfma_f32_16x16x32_bf16(pa, vb[kb][tb], oacc[half * 2 + tq][tb], 0, 0, 0);
            }
        }
    }
    bf16* obase = o + (size_t)win * 49 * 384 + h * 32;
#pragma unroll
    for (int ta = 0; ta < 4; ++ta) {
#pragma unroll
        for (int j = 0; j < 4; ++j) {
            int n = ta * 16 + hi * 4 + j;
            if (n < 49) {
#pragma unroll
                for (int tb = 0; tb < 2; ++tb)
                    obase[(size_t)n * 384 + tb * 16 + lo] = __float2bfloat16(oacc[ta][tb][j]);
            }
        }
    }
}

// C[M,N] = A[M,K] bf16 @ W[N,K]^T bf16. Whole-panel staging: BK=192 chunks,
// A[128][192]+W[64][192] in LDS (72 KB, 2 blocks/CU), ONE barrier pair per
// chunk, 6 k-steps of pure ds_read+MFMA (48 MFMA/wave per barrier).
// Slot-XOR swizzle (slot ^ (row&7)) applied on BOTH global source and LDS
// read keeps ds_read_b128 conflict-free (linear [*][192] would 2x the reads).
// grid = (N/64, M/128): consecutive blocks share the A panel via L2.
template <int K, int EPI>
__global__ __launch_bounds__(256) void gemm_bt(const bf16* __restrict__ A,
                                               const bf16* __restrict__ W,
                                               const float* __restrict__ bias,
                                               void* __restrict__ Cout,
                                               int N) {
    __shared__ __align__(16) bf16 lds_a[128 * 192];
    __shared__ __align__(16) bf16 lds_b[64 * 192];
    const int t = threadIdx.x;
    const int wave = t >> 6, lane = t & 63;
    const int n0 = blockIdx.x * 64, m0 = blockIdx.y * 128;
    const int wm = wave >> 1, wn = wave & 1;
    const int fr = lane & 15, hi = lane >> 4;
    f32x4 acc[4][2] = {};
    for (int kt = 0; kt < K; kt += 192) {
        if (kt > 0) __syncthreads();
#pragma unroll
        for (int i = 0; i < 12; ++i) {
            int u = i * 256 + t;
            int row = u / 24, slot = u % 24;
            int gslot = slot ^ (row & 7);
            async16((char*)lds_a + u * 16, A + (size_t)(m0 + row) * K + kt + gslot * 8);
        }
#pragma unroll
        for (int i = 0; i < 6; ++i) {
            int u = i * 256 + t;
            int row = u / 24, slot = u % 24;
            int gslot = slot ^ (row & 7);
            async16((char*)lds_b + u * 16, W + (size_t)(n0 + row) * K + kt + gslot * 8);
        }
        __syncthreads();
#pragma unroll
        for (int ks = 0; ks < 6; ++ks) {
            bf16x8 af[4], bfr[2];
#pragma unroll
            for (int mi = 0; mi < 4; ++mi) {
                int row = wm * 64 + mi * 16 + fr;
                int slot = (ks * 4 + hi) ^ (row & 7);
                af[mi] = *(const bf16x8*)((const char*)lds_a + row * 384 + slot * 16);
            }
#pragma unroll
            for (int ni = 0; ni < 2; ++ni) {
                int row = wn * 32 + ni * 16 + fr;
                int slot = (ks * 4 + hi) ^ (row & 7);
                bfr[ni] = *(const bf16x8*)((const char*)lds_b + row * 384 + slot * 16);
            }
#pragma unroll
            for (int mi = 0; mi < 4; ++mi)
#pragma unroll
                for (int ni = 0; ni < 2; ++ni)
                    acc[mi][ni] = __builtin_amdgcn_mfma_f32_16x16x32_bf16(af[mi], bfr[ni], acc[mi][ni], 0, 0, 0);
        }
    }
    const int rq4 = hi * 4;
#pragma unroll
    for (int mi = 0; mi < 4; ++mi) {
#pragma unroll
        for (int ni = 0; ni < 2; ++ni) {
            int gc = n0 + wn * 32 + ni * 16 + fr;
            float bv = bias ? bias[gc] : 0.0f;
            int grb = m0 + wm * 64 + mi * 16 + rq4;
#pragma unroll
            for (int j = 0; j < 4; ++j) {
                float v = acc[mi][ni][j] + bv;
                size_t idx = (size_t)(grb + j) * N + gc;
                if (EPI == 1) {
                    v = 0.5f * v * (1.0f + erff(v * 0.70710678118f));
                    ((bf16*)Cout)[idx] = __float2bfloat16(v);
                } else if (EPI == 2) {
                    float* Cf = (float*)Cout;
                    Cf[idx] = Cf[idx] + v;
                } else {
                    ((bf16*)Cout)[idx] = __float2bfloat16(v);
                }
            }
        }
    }
}

extern "C" void kernel_launch(void* const* d_in, const int* in_sizes, int n_in,
                              void* d_out, int out_size, void* d_ws, size_t ws_size,
                              hipStream_t stream) {
    const float* x      = (const float*)d_in[0];
    const float* n1g    = (const float*)d_in[1];
    const float* n1b    = (const float*)d_in[2];
    const float* rpbt   = (const float*)d_in[3];
    const float* qkv_v  = (const float*)d_in[4];
    const float* qkv_u  = (const float*)d_in[5];
    const float* qkv_b  = (const float*)d_in[6];
    const float* proj_v = (const float*)d_in[7];
    const float* proj_u = (const float*)d_in[8];
    const float* proj_b = (const float*)d_in[9];
    const float* n2g    = (const float*)d_in[10];
    const float* n2b    = (const float*)d_in[11];
    const float* fc1_v  = (const float*)d_in[12];
    const float* fc1_u  = (const float*)d_in[13];
    const float* fc1_b  = (const float*)d_in[14];
    const float* fc2_v  = (const float*)d_in[15];
    const float* fc2_u  = (const float*)d_in[16];
    const float* fc2_b  = (const float*)d_in[17];

    char* ws = (char*)d_ws;
    bf16* wb = (bf16*)ws;
    bf16* w_qkv_v  = wb;
    bf16* w_qkv_u  = wb + 73728;
    bf16* w_proj_v = wb + 294912;
    bf16* w_proj_u = wb + 368640;
    bf16* w_fc1_v  = wb + 442368;
    bf16* w_fc1_u  = wb + 516096;
    bf16* w_fc2_v  = wb + 811008;
    bf16* w_fc2_u  = wb + 1105920;
    size_t off = (size_t)4 << 20;
    bf16* R1 = (bf16*)(ws + off); off += (size_t)MROWS * 1536 * 2;   // qkv / proj / mlp-hidden
    bf16* R2 = (bf16*)(ws + off); off += (size_t)MROWS * 384 * 2;    // ywin / o / z
    bf16* R3 = (bf16*)(ws + off);                                    // t1/t2/t3/t4 (M x 192)
    float* out = (float*)d_out;

    Cvt8 c;
    c.s[0] = qkv_v;  c.d[0] = w_qkv_v;  c.n[0] = 73728;
    c.s[1] = qkv_u;  c.d[1] = w_qkv_u;  c.n[1] = 221184;
    c.s[2] = proj_v; c.d[2] = w_proj_v; c.n[2] = 73728;
    c.s[3] = proj_u; c.d[3] = w_proj_u; c.n[3] = 73728;
    c.s[4] = fc1_v;  c.d[4] = w_fc1_v;  c.n[4] = 73728;
    c.s[5] = fc1_u;  c.d[5] = w_fc1_u;  c.n[5] = 294912;
    c.s[6] = fc2_v;  c.d[6] = w_fc2_v;  c.n[6] = 294912;
    c.s[7] = fc2_u;  c.d[7] = w_fc2_u;  c.n[7] = 73728;
    cvt8_k<<<dim3(288, 8), 256, 0, stream>>>(c);

    ln1_window_k<<<MROWS / 4, 256, 0, stream>>>(x, n1g, n1b, R2);
    gemm_bt<384, 0><<<dim3(3, 784), 256, 0, stream>>>(R2, w_qkv_v, nullptr, R3, 192);
    gemm_bt<192, 0><<<dim3(18, 784), 256, 0, stream>>>(R3, w_qkv_u, qkv_b, R1, 1152);
    attn_mfma_k<<<dim3(2048, 3), 256, 0, stream>>>(R1, rpbt, R2);
    gemm_bt<384, 0><<<dim3(3, 784), 256, 0, stream>>>(R2, w_proj_v, nullptr, R3, 192);
    gemm_bt<192, 0><<<dim3(6, 784), 256, 0, stream>>>(R3, w_proj_u, proj_b, R1, 384);
    resid_ln2_k<<<MROWS / 4, 256, 0, stream>>>(x, R1, n2g, n2b, out, R2);
    gemm_bt<384, 0><<<dim3(3, 784), 256, 0, stream>>>(R2, w_fc1_v, nullptr, R3, 192);
    gemm_bt<192, 1><<<dim3(24, 784), 256, 0, stream>>>(R3, w_fc1_u, fc1_b, R1, 1536);
    gemm_bt<1536, 0><<<dim3(3, 784), 256, 0, stream>>>(R1, w_fc2_v, nullptr, R3, 192);
    gemm_bt<192, 2><<<dim3(6, 784), 256, 0, stream>>>(R3, w_fc2_u, fc2_b, out, 384);
}

// Round 6
// 933.610 us; speedup vs baseline: 1.6463x; 1.2543x over previous
//
#include <hip/hip_runtime.h>
#include <hip/hip_bf16.h>

using bf16 = __hip_bfloat16;
typedef __bf16 bf16x8 __attribute__((ext_vector_type(8)));
typedef float f32x4 __attribute__((ext_vector_type(4)));

#define MROWS 100352   // 2048 windows * 49 tokens = 32*3136

__device__ __forceinline__ void async16(void* l, const void* g) {
    void* gg = const_cast<void*>(g);
    __builtin_amdgcn_global_load_lds((__attribute__((address_space(1))) void*)gg,
                                     (__attribute__((address_space(3))) void*)l, 16, 0, 0);
}

// stable tanh-approx GELU: max err vs exact erf-GELU ~7e-4, inf-safe
__device__ __forceinline__ float gelu_f(float x) {
    float u = 0.7978845608028654f * (x + 0.044715f * x * x * x);
    float e = __expf(2.0f * u);
    float t = 1.0f - 2.0f / (e + 1.0f);   // tanh(u); e=inf -> 1, e=0 -> -1
    return 0.5f * x * (1.0f + t);
}

struct Cvt8 { const float* s[8]; bf16* d[8]; int n[8]; };

__global__ __launch_bounds__(256) void cvt8_k(Cvt8 c) {
    int seg = blockIdx.y;
    int i4 = (blockIdx.x * 256 + threadIdx.x) * 4;
    if (i4 < c.n[seg]) {
        float4 v = *(const float4*)(c.s[seg] + i4);
        bf16* d = c.d[seg] + i4;
        d[0] = __float2bfloat16(v.x);
        d[1] = __float2bfloat16(v.y);
        d[2] = __float2bfloat16(v.z);
        d[3] = __float2bfloat16(v.w);
    }
}

// LN1 + cyclic shift(-3,-3) + window partition. One wave per output row.
__global__ __launch_bounds__(256) void ln1_window_k(const float* __restrict__ x,
                                                    const float* __restrict__ g,
                                                    const float* __restrict__ bta,
                                                    bf16* __restrict__ ywin) {
    int wrow = blockIdx.x * 4 + (threadIdx.x >> 6);
    int lane = threadIdx.x & 63;
    int tok = wrow % 49, win = wrow / 49;
    int i = tok / 7, j = tok % 7;
    int wwi = win & 7, whi = (win >> 3) & 7, bi = win >> 6;
    int hs = (whi * 7 + i + 3) % 56;
    int ws_ = (wwi * 7 + j + 3) % 56;
    const float* xr = x + ((size_t)bi * 3136 + (size_t)hs * 56 + ws_) * 384;
    float v[6]; float s = 0.f, s2 = 0.f;
#pragma unroll
    for (int u = 0; u < 6; ++u) { float t = xr[lane + 64 * u]; v[u] = t; s += t; s2 += t * t; }
#pragma unroll
    for (int d = 1; d < 64; d <<= 1) { s += __shfl_xor(s, d); s2 += __shfl_xor(s2, d); }
    float mean = s * (1.0f / 384.0f);
    float var = s2 * (1.0f / 384.0f) - mean * mean;
    float rstd = rsqrtf(var + 1e-5f);
    bf16* yr = ywin + (size_t)wrow * 384;
#pragma unroll
    for (int u = 0; u < 6; ++u) {
        int c = lane + 64 * u;
        yr[c] = __float2bfloat16((v[u] - mean) * rstd * g[c] + bta[c]);
    }
}

// residual add (window-reverse + roll(+3,+3)) + LN2. x2 -> d_out (fp32), z -> bf16
__global__ __launch_bounds__(256) void resid_ln2_k(const float* __restrict__ x,
                                                   const bf16* __restrict__ proj,
                                                   const float* __restrict__ g,
                                                   const float* __restrict__ bta,
                                                   float* __restrict__ x2,
                                                   bf16* __restrict__ z) {
    int row = blockIdx.x * 4 + (threadIdx.x >> 6);
    int lane = threadIdx.x & 63;
    int bi = row / 3136; int hw = row % 3136;
    int h = hw / 56, w = hw % 56;
    int h2 = (h + 53) % 56, w2 = (w + 53) % 56;
    int prow = ((bi * 8 + h2 / 7) * 8 + w2 / 7) * 49 + (h2 % 7) * 7 + (w2 % 7);
    const float* xr = x + (size_t)row * 384;
    const bf16* pr = proj + (size_t)prow * 384;
    float* x2r = x2 + (size_t)row * 384;
    float v[6]; float s = 0.f, s2 = 0.f;
#pragma unroll
    for (int u = 0; u < 6; ++u) {
        int c = lane + 64 * u;
        float t = xr[c] + __bfloat162float(pr[c]);
        v[u] = t; s += t; s2 += t * t;
        x2r[c] = t;
    }
#pragma unroll
    for (int d = 1; d < 64; d <<= 1) { s += __shfl_xor(s, d); s2 += __shfl_xor(s2, d); }
    float mean = s * (1.0f / 384.0f);
    float var = s2 * (1.0f / 384.0f) - mean * mean;
    float rstd = rsqrtf(var + 1e-5f);
    bf16* zr = z + (size_t)row * 384;
#pragma unroll
    for (int u = 0; u < 6; ++u) {
        int c = lane + 64 * u;
        zr[c] = __float2bfloat16((v[u] - mean) * rstd * g[c] + bta[c]);
    }
}

// MFMA windowed attention: grid (2048 windows, 3 head-groups); 4 waves,
// one wave per head; one round per block.
__global__ __launch_bounds__(256) void attn_mfma_k(const bf16* __restrict__ qkv,
                                                   const float* __restrict__ rpbt,
                                                   bf16* __restrict__ o) {
    __shared__ __align__(16) __bf16 vt_s[4][32 * 72];   // V^T  [d][m], m padded to 64
    __shared__ __align__(16) __bf16 p_s[4][32 * 72];    // P half [n_loc][m]
    __shared__ float rpb_sh[676];                       // [ridx][4 heads of this group]
    const int win = blockIdx.x;
    const int r = blockIdx.y;
    const int wave = threadIdx.x >> 6, lane = threadIdx.x & 63;
    const int lo = lane & 15, hi = lane >> 4;
    const int whi = (win >> 3) & 7, wwi = win & 7;
    const bool bH = (whi == 7), bW = (wwi == 7);
    const bool boundary = bH || bW;
    __bf16* vt_w = vt_s[wave];
    __bf16* p_w = p_s[wave];
    const int h = r * 4 + wave;
    const bf16* qbase = qkv + (size_t)win * 49 * 1152 + h * 32;
    bf16x8 zf = {};

    for (int idx = threadIdx.x; idx < 676; idx += 256)
        rpb_sh[idx] = rpbt[(idx >> 2) * 12 + r * 4 + (idx & 3)];
    __syncthreads();

    // V -> LDS transposed; lane handles column m (write banks 2-way = free)
    {
        int m = lane;
        bf16x8 vrow[4];
#pragma unroll
        for (int d8 = 0; d8 < 4; ++d8)
            vrow[d8] = (m < 49) ? *(const bf16x8*)(qbase + (size_t)m * 1152 + 768 + d8 * 8) : zf;
#pragma unroll
        for (int d8 = 0; d8 < 4; ++d8)
#pragma unroll
            for (int e = 0; e < 8; ++e)
                vt_w[(d8 * 8 + e) * 72 + m] = vrow[d8][e];
    }
    // Q/K fragments directly from global (K-dim = 32 = one MFMA k-step)
    bf16x8 aq[4], bk[4];
    const int kq = hi * 8;
#pragma unroll
    for (int ta = 0; ta < 4; ++ta) {
        int n = ta * 16 + lo;
        aq[ta] = (n < 49) ? *(const bf16x8*)(qbase + (size_t)n * 1152 + kq) : zf;
        bk[ta] = (n < 49) ? *(const bf16x8*)(qbase + (size_t)n * 1152 + 384 + kq) : zf;
    }
    // S = Q K^T : acc[ta][tb], row n = 16ta+4hi+j, col m = 16tb+lo
    f32x4 acc[4][4] = {};
#pragma unroll
    for (int ta = 0; ta < 4; ++ta)
#pragma unroll
        for (int tb = 0; tb < 4; ++tb)
            acc[ta][tb] = __builtin_amdgcn_mfma_f32_16x16x32_bf16(aq[ta], bk[tb], acc[ta][tb], 0, 0, 0);
    // scale + rpb + shift-mask (in place)
    int i2[4], j2[4], rm[4];
#pragma unroll
    for (int tb = 0; tb < 4; ++tb) {
        int m = tb * 16 + lo;
        int mm = m < 49 ? m : 0;
        i2[tb] = mm / 7; j2[tb] = mm % 7;
        rm[tb] = (bH ? (i2[tb] < 4 ? 1 : 2) : 0) * 3 + (bW ? (j2[tb] < 4 ? 1 : 2) : 0);
    }
#pragma unroll
    for (int ta = 0; ta < 4; ++ta) {
#pragma unroll
        for (int j = 0; j < 4; ++j) {
            int n = ta * 16 + hi * 4 + j;
            int nn = n < 49 ? n : 0;
            int i1 = nn / 7, j1 = nn % 7;
            int rn = (bH ? (i1 < 4 ? 1 : 2) : 0) * 3 + (bW ? (j1 < 4 ? 1 : 2) : 0);
#pragma unroll
            for (int tb = 0; tb < 4; ++tb) {
                int m = tb * 16 + lo;
                float v;
                if (n < 49 && m < 49) {
                    v = acc[ta][tb][j] * 0.17677669529663687f
                        + rpb_sh[((i1 - i2[tb] + 6) * 13 + (j1 - j2[tb] + 6)) * 4 + wave];
                    if (boundary && rn != rm[tb]) v -= 100.0f;
                } else {
                    v = -1e30f;
                }
                acc[ta][tb][j] = v;
            }
        }
    }
    // V^T fragments (B-operand) hoisted once
    bf16x8 vb[2][2];
#pragma unroll
    for (int kb = 0; kb < 2; ++kb)
#pragma unroll
        for (int tb = 0; tb < 2; ++tb)
            vb[kb][tb] = *(const bf16x8*)(vt_w + (tb * 16 + lo) * 72 + kb * 32 + hi * 8);

    f32x4 oacc[4][2] = {};
    // two halves of 32 rows: softmax -> P half tile -> PV
#pragma unroll
    for (int half = 0; half < 2; ++half) {
#pragma unroll
        for (int tq = 0; tq < 2; ++tq) {
            int ta = half * 2 + tq;
#pragma unroll
            for (int j = 0; j < 4; ++j) {
                float mx = fmaxf(fmaxf(acc[ta][0][j], acc[ta][1][j]),
                                 fmaxf(acc[ta][2][j], acc[ta][3][j]));
                mx = fmaxf(mx, __shfl_xor(mx, 1));
                mx = fmaxf(mx, __shfl_xor(mx, 2));
                mx = fmaxf(mx, __shfl_xor(mx, 4));
                mx = fmaxf(mx, __shfl_xor(mx, 8));
                float e0 = __expf(acc[ta][0][j] - mx);
                float e1 = __expf(acc[ta][1][j] - mx);
                float e2 = __expf(acc[ta][2][j] - mx);
                float e3 = __expf(acc[ta][3][j] - mx);
                float sm = e0 + e1 + e2 + e3;
                sm += __shfl_xor(sm, 1);
                sm += __shfl_xor(sm, 2);
                sm += __shfl_xor(sm, 4);
                sm += __shfl_xor(sm, 8);
                float inv = 1.0f / sm;
                int nl = tq * 16 + hi * 4 + j;
                p_w[nl * 72 + lo]      = (__bf16)(e0 * inv);
                p_w[nl * 72 + 16 + lo] = (__bf16)(e1 * inv);
                p_w[nl * 72 + 32 + lo] = (__bf16)(e2 * inv);
                p_w[nl * 72 + 48 + lo] = (__bf16)(e3 * inv);
            }
        }
#pragma unroll
        for (int kb = 0; kb < 2; ++kb) {
#pragma unroll
            for (int tq = 0; tq < 2; ++tq) {
                bf16x8 pa = *(const bf16x8*)(p_w + (tq * 16 + lo) * 72 + kb * 32 + hi * 8);
#pragma unroll
                for (int tb = 0; tb < 2; ++tb)
                    oacc[half * 2 + tq][tb] =
                        __builtin_amdgcn_mfma_f32_16x16x32_bf16(pa, vb[kb][tb], oacc[half * 2 + tq][tb], 0, 0, 0);
            }
        }
    }
    bf16* obase = o + (size_t)win * 49 * 384 + h * 32;
#pragma unroll
    for (int ta = 0; ta < 4; ++ta) {
#pragma unroll
        for (int j = 0; j < 4; ++j) {
            int n = ta * 16 + hi * 4 + j;
            if (n < 49) {
#pragma unroll
                for (int tb = 0; tb < 2; ++tb)
                    obase[(size_t)n * 384 + tb * 16 + lo] = __float2bfloat16(oacc[ta][tb][j]);
            }
        }
    }
}

// C[M,N] = A[M,K] bf16 @ W[N,K]^T bf16.  BK=64: LDS 24 KB -> 6 blocks/CU
// (these GEMMs are epilogue/VALU-bound at low K; occupancy saturates VALU).
// Row = 64 elem = 128 B = one bank-row; slot ^ (row&7) over the 8 16B slots
// is the exact st-pattern (bijective, measured 0 conflicts at BK=192 analog).
// grid = (N/64, M/128): consecutive blocks share the A panel via L2.
template <int K, int EPI>
__global__ __launch_bounds__(256) void gemm_bt(const bf16* __restrict__ A,
                                               const bf16* __restrict__ W,
                                               const float* __restrict__ bias,
                                               void* __restrict__ Cout,
                                               int N) {
    __shared__ __align__(16) bf16 lds_a[128 * 64];
    __shared__ __align__(16) bf16 lds_b[64 * 64];
    const int t = threadIdx.x;
    const int wave = t >> 6, lane = t & 63;
    const int n0 = blockIdx.x * 64, m0 = blockIdx.y * 128;
    const int wm = wave >> 1, wn = wave & 1;
    const int fr = lane & 15, hi = lane >> 4;
    f32x4 acc[4][2] = {};
    for (int kt = 0; kt < K; kt += 64) {
        if (kt > 0) __syncthreads();
#pragma unroll
        for (int i = 0; i < 4; ++i) {
            int u = i * 256 + t;
            int row = u >> 3, slot = u & 7;
            int gslot = slot ^ (row & 7);
            async16((char*)lds_a + u * 16, A + (size_t)(m0 + row) * K + kt + gslot * 8);
        }
#pragma unroll
        for (int i = 0; i < 2; ++i) {
            int u = i * 256 + t;
            int row = u >> 3, slot = u & 7;
            int gslot = slot ^ (row & 7);
            async16((char*)lds_b + u * 16, W + (size_t)(n0 + row) * K + kt + gslot * 8);
        }
        __syncthreads();
#pragma unroll
        for (int ks = 0; ks < 2; ++ks) {
            bf16x8 af[4], bfr[2];
#pragma unroll
            for (int mi = 0; mi < 4; ++mi) {
                int row = wm * 64 + mi * 16 + fr;
                int slot = (ks * 4 + hi) ^ (row & 7);
                af[mi] = *(const bf16x8*)((const char*)lds_a + row * 128 + slot * 16);
            }
#pragma unroll
            for (int ni = 0; ni < 2; ++ni) {
                int row = wn * 32 + ni * 16 + fr;
                int slot = (ks * 4 + hi) ^ (row & 7);
                bfr[ni] = *(const bf16x8*)((const char*)lds_b + row * 128 + slot * 16);
            }
#pragma unroll
            for (int mi = 0; mi < 4; ++mi)
#pragma unroll
                for (int ni = 0; ni < 2; ++ni)
                    acc[mi][ni] = __builtin_amdgcn_mfma_f32_16x16x32_bf16(af[mi], bfr[ni], acc[mi][ni], 0, 0, 0);
        }
    }
    const int rq4 = hi * 4;
#pragma unroll
    for (int mi = 0; mi < 4; ++mi) {
#pragma unroll
        for (int ni = 0; ni < 2; ++ni) {
            int gc = n0 + wn * 32 + ni * 16 + fr;
            float bv = bias ? bias[gc] : 0.0f;
            int grb = m0 + wm * 64 + mi * 16 + rq4;
#pragma unroll
            for (int j = 0; j < 4; ++j) {
                float v = acc[mi][ni][j] + bv;
                size_t idx = (size_t)(grb + j) * N + gc;
                if (EPI == 1) {
                    ((bf16*)Cout)[idx] = __float2bfloat16(gelu_f(v));
                } else if (EPI == 2) {
                    float* Cf = (float*)Cout;
                    Cf[idx] = Cf[idx] + v;
                } else {
                    ((bf16*)Cout)[idx] = __float2bfloat16(v);
                }
            }
        }
    }
}

extern "C" void kernel_launch(void* const* d_in, const int* in_sizes, int n_in,
                              void* d_out, int out_size, void* d_ws, size_t ws_size,
                              hipStream_t stream) {
    const float* x      = (const float*)d_in[0];
    const float* n1g    = (const float*)d_in[1];
    const float* n1b    = (const float*)d_in[2];
    const float* rpbt   = (const float*)d_in[3];
    const float* qkv_v  = (const float*)d_in[4];
    const float* qkv_u  = (const float*)d_in[5];
    const float* qkv_b  = (const float*)d_in[6];
    const float* proj_v = (const float*)d_in[7];
    const float* proj_u = (const float*)d_in[8];
    const float* proj_b = (const float*)d_in[9];
    const float* n2g    = (const float*)d_in[10];
    const float* n2b    = (const float*)d_in[11];
    const float* fc1_v  = (const float*)d_in[12];
    const float* fc1_u  = (const float*)d_in[13];
    const float* fc1_b  = (const float*)d_in[14];
    const float* fc2_v  = (const float*)d_in[15];
    const float* fc2_u  = (const float*)d_in[16];
    const float* fc2_b  = (const float*)d_in[17];

    char* ws = (char*)d_ws;
    bf16* wb = (bf16*)ws;
    bf16* w_qkv_v  = wb;
    bf16* w_qkv_u  = wb + 73728;
    bf16* w_proj_v = wb + 294912;
    bf16* w_proj_u = wb + 368640;
    bf16* w_fc1_v  = wb + 442368;
    bf16* w_fc1_u  = wb + 516096;
    bf16* w_fc2_v  = wb + 811008;
    bf16* w_fc2_u  = wb + 1105920;
    size_t off = (size_t)4 << 20;
    bf16* R1 = (bf16*)(ws + off); off += (size_t)MROWS * 1536 * 2;   // qkv / proj / mlp-hidden
    bf16* R2 = (bf16*)(ws + off); off += (size_t)MROWS * 384 * 2;    // ywin / o / z
    bf16* R3 = (bf16*)(ws + off);                                    // t1/t2/t3/t4 (M x 192)
    float* out = (float*)d_out;

    Cvt8 c;
    c.s[0] = qkv_v;  c.d[0] = w_qkv_v;  c.n[0] = 73728;
    c.s[1] = qkv_u;  c.d[1] = w_qkv_u;  c.n[1] = 221184;
    c.s[2] = proj_v; c.d[2] = w_proj_v; c.n[2] = 73728;
    c.s[3] = proj_u; c.d[3] = w_proj_u; c.n[3] = 73728;
    c.s[4] = fc1_v;  c.d[4] = w_fc1_v;  c.n[4] = 73728;
    c.s[5] = fc1_u;  c.d[5] = w_fc1_u;  c.n[5] = 294912;
    c.s[6] = fc2_v;  c.d[6] = w_fc2_v;  c.n[6] = 294912;
    c.s[7] = fc2_u;  c.d[7] = w_fc2_u;  c.n[7] = 73728;
    cvt8_k<<<dim3(288, 8), 256, 0, stream>>>(c);

    ln1_window_k<<<MROWS / 4, 256, 0, stream>>>(x, n1g, n1b, R2);
    gemm_bt<384, 0><<<dim3(3, 784), 256, 0, stream>>>(R2, w_qkv_v, nullptr, R3, 192);
    gemm_bt<192, 0><<<dim3(18, 784), 256, 0, stream>>>(R3, w_qkv_u, qkv_b, R1, 1152);
    attn_mfma_k<<<dim3(2048, 3), 256, 0, stream>>>(R1, rpbt, R2);
    gemm_bt<384, 0><<<dim3(3, 784), 256, 0, stream>>>(R2, w_proj_v, nullptr, R3, 192);
    gemm_bt<192, 0><<<dim3(6, 784), 256, 0, stream>>>(R3, w_proj_u, proj_b, R1, 384);
    resid_ln2_k<<<MROWS / 4, 256, 0, stream>>>(x, R1, n2g, n2b, out, R2);
    gemm_bt<384, 0><<<dim3(3, 784), 256, 0, stream>>>(R2, w_fc1_v, nullptr, R3, 192);
    gemm_bt<192, 1><<<dim3(24, 784), 256, 0, stream>>>(R3, w_fc1_u, fc1_b, R1, 1536);
    gemm_bt<1536, 0><<<dim3(3, 784), 256, 0, stream>>>(R1, w_fc2_v, nullptr, R3, 192);
    gemm_bt<192, 2><<<dim3(6, 784), 256, 0, stream>>>(R3, w_fc2_u, fc2_b, out, 384);
}

// Round 7
// 900.513 us; speedup vs baseline: 1.7068x; 1.0368x over previous
//
#include <hip/hip_runtime.h>
#include <hip/hip_bf16.h>

using bf16 = __hip_bfloat16;
typedef __bf16 bf16x8 __attribute__((ext_vector_type(8)));
typedef float f32x4 __attribute__((ext_vector_type(4)));

#define MROWS 100352   // 2048 windows * 49 tokens = 32*3136

__device__ __forceinline__ void async16(void* l, const void* g) {
    void* gg = const_cast<void*>(g);
    __builtin_amdgcn_global_load_lds((__attribute__((address_space(1))) void*)gg,
                                     (__attribute__((address_space(3))) void*)l, 16, 0, 0);
}

// stable tanh-approx GELU: max err vs exact erf-GELU ~7e-4, inf-safe
__device__ __forceinline__ float gelu_f(float x) {
    float u = 0.7978845608028654f * (x + 0.044715f * x * x * x);
    float e = __expf(2.0f * u);
    float t = 1.0f - 2.0f / (e + 1.0f);   // tanh(u); e=inf -> 1, e=0 -> -1
    return 0.5f * x * (1.0f + t);
}

__device__ __forceinline__ unsigned short bfu(float x) {
    bf16 b = __float2bfloat16(x);
    union { bf16 b; unsigned short u; } c; c.b = b; return c.u;
}

struct Cvt8 { const float* s[8]; bf16* d[8]; int n[8]; };

__global__ __launch_bounds__(256) void cvt8_k(Cvt8 c) {
    int seg = blockIdx.y;
    int i4 = (blockIdx.x * 256 + threadIdx.x) * 4;
    if (i4 < c.n[seg]) {
        float4 v = *(const float4*)(c.s[seg] + i4);
        bf16* d = c.d[seg] + i4;
        d[0] = __float2bfloat16(v.x);
        d[1] = __float2bfloat16(v.y);
        d[2] = __float2bfloat16(v.z);
        d[3] = __float2bfloat16(v.w);
    }
}

// LN1 + cyclic shift(-3,-3) + window partition. One wave per output row.
__global__ __launch_bounds__(256) void ln1_window_k(const float* __restrict__ x,
                                                    const float* __restrict__ g,
                                                    const float* __restrict__ bta,
                                                    bf16* __restrict__ ywin) {
    int wrow = blockIdx.x * 4 + (threadIdx.x >> 6);
    int lane = threadIdx.x & 63;
    int tok = wrow % 49, win = wrow / 49;
    int i = tok / 7, j = tok % 7;
    int wwi = win & 7, whi = (win >> 3) & 7, bi = win >> 6;
    int hs = (whi * 7 + i + 3) % 56;
    int ws_ = (wwi * 7 + j + 3) % 56;
    const float* xr = x + ((size_t)bi * 3136 + (size_t)hs * 56 + ws_) * 384;
    float v[6]; float s = 0.f, s2 = 0.f;
#pragma unroll
    for (int u = 0; u < 6; ++u) { float t = xr[lane + 64 * u]; v[u] = t; s += t; s2 += t * t; }
#pragma unroll
    for (int d = 1; d < 64; d <<= 1) { s += __shfl_xor(s, d); s2 += __shfl_xor(s2, d); }
    float mean = s * (1.0f / 384.0f);
    float var = s2 * (1.0f / 384.0f) - mean * mean;
    float rstd = rsqrtf(var + 1e-5f);
    bf16* yr = ywin + (size_t)wrow * 384;
#pragma unroll
    for (int u = 0; u < 6; ++u) {
        int c = lane + 64 * u;
        yr[c] = __float2bfloat16((v[u] - mean) * rstd * g[c] + bta[c]);
    }
}

// residual add (window-reverse + roll(+3,+3)) + LN2. x2 -> d_out (fp32), z -> bf16
__global__ __launch_bounds__(256) void resid_ln2_k(const float* __restrict__ x,
                                                   const bf16* __restrict__ proj,
                                                   const float* __restrict__ g,
                                                   const float* __restrict__ bta,
                                                   float* __restrict__ x2,
                                                   bf16* __restrict__ z) {
    int row = blockIdx.x * 4 + (threadIdx.x >> 6);
    int lane = threadIdx.x & 63;
    int bi = row / 3136; int hw = row % 3136;
    int h = hw / 56, w = hw % 56;
    int h2 = (h + 53) % 56, w2 = (w + 53) % 56;
    int prow = ((bi * 8 + h2 / 7) * 8 + w2 / 7) * 49 + (h2 % 7) * 7 + (w2 % 7);
    const float* xr = x + (size_t)row * 384;
    const bf16* pr = proj + (size_t)prow * 384;
    float* x2r = x2 + (size_t)row * 384;
    float v[6]; float s = 0.f, s2 = 0.f;
#pragma unroll
    for (int u = 0; u < 6; ++u) {
        int c = lane + 64 * u;
        float t = xr[c] + __bfloat162float(pr[c]);
        v[u] = t; s += t; s2 += t * t;
        x2r[c] = t;
    }
#pragma unroll
    for (int d = 1; d < 64; d <<= 1) { s += __shfl_xor(s, d); s2 += __shfl_xor(s2, d); }
    float mean = s * (1.0f / 384.0f);
    float var = s2 * (1.0f / 384.0f) - mean * mean;
    float rstd = rsqrtf(var + 1e-5f);
    bf16* zr = z + (size_t)row * 384;
#pragma unroll
    for (int u = 0; u < 6; ++u) {
        int c = lane + 64 * u;
        zr[c] = __float2bfloat16((v[u] - mean) * rstd * g[c] + bta[c]);
    }
}

// MFMA windowed attention: grid (2048 windows, 3 head-groups); 4 waves,
// one wave per head; one round per block.
__global__ __launch_bounds__(256) void attn_mfma_k(const bf16* __restrict__ qkv,
                                                   const float* __restrict__ rpbt,
                                                   bf16* __restrict__ o) {
    __shared__ __align__(16) __bf16 vt_s[4][32 * 72];   // V^T  [d][m], m padded to 64
    __shared__ __align__(16) __bf16 p_s[4][32 * 72];    // P half [n_loc][m]
    __shared__ float rpb_sh[676];                       // [ridx][4 heads of this group]
    const int win = blockIdx.x;
    const int r = blockIdx.y;
    const int wave = threadIdx.x >> 6, lane = threadIdx.x & 63;
    const int lo = lane & 15, hi = lane >> 4;
    const int whi = (win >> 3) & 7, wwi = win & 7;
    const bool bH = (whi == 7), bW = (wwi == 7);
    const bool boundary = bH || bW;
    __bf16* vt_w = vt_s[wave];
    __bf16* p_w = p_s[wave];
    const int h = r * 4 + wave;
    const bf16* qbase = qkv + (size_t)win * 49 * 1152 + h * 32;
    bf16x8 zf = {};

    for (int idx = threadIdx.x; idx < 676; idx += 256)
        rpb_sh[idx] = rpbt[(idx >> 2) * 12 + r * 4 + (idx & 3)];
    __syncthreads();

    // V -> LDS transposed; lane handles column m (write banks 2-way = free)
    {
        int m = lane;
        bf16x8 vrow[4];
#pragma unroll
        for (int d8 = 0; d8 < 4; ++d8)
            vrow[d8] = (m < 49) ? *(const bf16x8*)(qbase + (size_t)m * 1152 + 768 + d8 * 8) : zf;
#pragma unroll
        for (int d8 = 0; d8 < 4; ++d8)
#pragma unroll
            for (int e = 0; e < 8; ++e)
                vt_w[(d8 * 8 + e) * 72 + m] = vrow[d8][e];
    }
    // Q/K fragments directly from global (K-dim = 32 = one MFMA k-step)
    bf16x8 aq[4], bk[4];
    const int kq = hi * 8;
#pragma unroll
    for (int ta = 0; ta < 4; ++ta) {
        int n = ta * 16 + lo;
        aq[ta] = (n < 49) ? *(const bf16x8*)(qbase + (size_t)n * 1152 + kq) : zf;
        bk[ta] = (n < 49) ? *(const bf16x8*)(qbase + (size_t)n * 1152 + 384 + kq) : zf;
    }
    // S = Q K^T : acc[ta][tb], row n = 16ta+4hi+j, col m = 16tb+lo
    f32x4 acc[4][4] = {};
#pragma unroll
    for (int ta = 0; ta < 4; ++ta)
#pragma unroll
        for (int tb = 0; tb < 4; ++tb)
            acc[ta][tb] = __builtin_amdgcn_mfma_f32_16x16x32_bf16(aq[ta], bk[tb], acc[ta][tb], 0, 0, 0);
    // scale + rpb + shift-mask (in place)
    int i2[4], j2[4], rm[4];
#pragma unroll
    for (int tb = 0; tb < 4; ++tb) {
        int m = tb * 16 + lo;
        int mm = m < 49 ? m : 0;
        i2[tb] = mm / 7; j2[tb] = mm % 7;
        rm[tb] = (bH ? (i2[tb] < 4 ? 1 : 2) : 0) * 3 + (bW ? (j2[tb] < 4 ? 1 : 2) : 0);
    }
#pragma unroll
    for (int ta = 0; ta < 4; ++ta) {
#pragma unroll
        for (int j = 0; j < 4; ++j) {
            int n = ta * 16 + hi * 4 + j;
            int nn = n < 49 ? n : 0;
            int i1 = nn / 7, j1 = nn % 7;
            int rn = (bH ? (i1 < 4 ? 1 : 2) : 0) * 3 + (bW ? (j1 < 4 ? 1 : 2) : 0);
#pragma unroll
            for (int tb = 0; tb < 4; ++tb) {
                int m = tb * 16 + lo;
                float v;
                if (n < 49 && m < 49) {
                    v = acc[ta][tb][j] * 0.17677669529663687f
                        + rpb_sh[((i1 - i2[tb] + 6) * 13 + (j1 - j2[tb] + 6)) * 4 + wave];
                    if (boundary && rn != rm[tb]) v -= 100.0f;
                } else {
                    v = -1e30f;
                }
                acc[ta][tb][j] = v;
            }
        }
    }
    // V^T fragments (B-operand) hoisted once
    bf16x8 vb[2][2];
#pragma unroll
    for (int kb = 0; kb < 2; ++kb)
#pragma unroll
        for (int tb = 0; tb < 2; ++tb)
            vb[kb][tb] = *(const bf16x8*)(vt_w + (tb * 16 + lo) * 72 + kb * 32 + hi * 8);

    f32x4 oacc[4][2] = {};
    // two halves of 32 rows: softmax -> P half tile -> PV
#pragma unroll
    for (int half = 0; half < 2; ++half) {
#pragma unroll
        for (int tq = 0; tq < 2; ++tq) {
            int ta = half * 2 + tq;
#pragma unroll
            for (int j = 0; j < 4; ++j) {
                float mx = fmaxf(fmaxf(acc[ta][0][j], acc[ta][1][j]),
                                 fmaxf(acc[ta][2][j], acc[ta][3][j]));
                mx = fmaxf(mx, __shfl_xor(mx, 1));
                mx = fmaxf(mx, __shfl_xor(mx, 2));
                mx = fmaxf(mx, __shfl_xor(mx, 4));
                mx = fmaxf(mx, __shfl_xor(mx, 8));
                float e0 = __expf(acc[ta][0][j] - mx);
                float e1 = __expf(acc[ta][1][j] - mx);
                float e2 = __expf(acc[ta][2][j] - mx);
                float e3 = __expf(acc[ta][3][j] - mx);
                float sm = e0 + e1 + e2 + e3;
                sm += __shfl_xor(sm, 1);
                sm += __shfl_xor(sm, 2);
                sm += __shfl_xor(sm, 4);
                sm += __shfl_xor(sm, 8);
                float inv = 1.0f / sm;
                int nl = tq * 16 + hi * 4 + j;
                p_w[nl * 72 + lo]      = (__bf16)(e0 * inv);
                p_w[nl * 72 + 16 + lo] = (__bf16)(e1 * inv);
                p_w[nl * 72 + 32 + lo] = (__bf16)(e2 * inv);
                p_w[nl * 72 + 48 + lo] = (__bf16)(e3 * inv);
            }
        }
#pragma unroll
        for (int kb = 0; kb < 2; ++kb) {
#pragma unroll
            for (int tq = 0; tq < 2; ++tq) {
                bf16x8 pa = *(const bf16x8*)(p_w + (tq * 16 + lo) * 72 + kb * 32 + hi * 8);
#pragma unroll
                for (int tb = 0; tb < 2; ++tb)
                    oacc[half * 2 + tq][tb] =
                        __builtin_amdgcn_mfma_f32_16x16x32_bf16(pa, vb[kb][tb], oacc[half * 2 + tq][tb], 0, 0, 0);
            }
        }
    }
    bf16* obase = o + (size_t)win * 49 * 384 + h * 32;
#pragma unroll
    for (int ta = 0; ta < 4; ++ta) {
#pragma unroll
        for (int j = 0; j < 4; ++j) {
            int n = ta * 16 + hi * 4 + j;
            if (n < 49) {
#pragma unroll
                for (int tb = 0; tb < 2; ++tb)
                    obase[(size_t)n * 384 + tb * 16 + lo] = __float2bfloat16(oacc[ta][tb][j]);
            }
        }
    }
}

// C[M,N] = A[M,K] bf16 @ W[N,K]^T bf16.  BK=64, 24 KB LDS -> 6 blocks/CU.
// SWAPPED operands: acc = mfma(W_frag, A_frag) so each lane holds 4
// CONSECUTIVE N columns (n = ntile+4hi+j, m = mtile+lo) -> packed 8B stores,
// one addr per fragment, float4 bias, float4 RMW for EPI=2.
// XCD-chunked swizzle: consecutive x-tiles (sharing an A-panel) land on one
// XCD -> A fetched once from HBM (nwg%8==0 since gridDim.y=784).
template <int K, int EPI>
__global__ __launch_bounds__(256) void gemm_bt(const bf16* __restrict__ A,
                                               const bf16* __restrict__ W,
                                               const float* __restrict__ bias,
                                               void* __restrict__ Cout,
                                               int N) {
    __shared__ __align__(16) bf16 lds_a[128 * 64];
    __shared__ __align__(16) bf16 lds_b[64 * 64];
    const int t = threadIdx.x;
    const int wave = t >> 6, lane = t & 63;
    const int gdx = gridDim.x;
    int flat = blockIdx.y * gdx + blockIdx.x;
    int q = (gdx * gridDim.y) >> 3;
    int work = (flat & 7) * q + (flat >> 3);
    const int n0 = (work % gdx) * 64, m0 = (work / gdx) * 128;
    const int wm = wave >> 1, wn = wave & 1;
    const int fr = lane & 15, hi = lane >> 4;
    f32x4 acc[4][2] = {};
    for (int kt = 0; kt < K; kt += 64) {
        if (kt > 0) __syncthreads();
#pragma unroll
        for (int i = 0; i < 4; ++i) {
            int u = i * 256 + t;
            int row = u >> 3, slot = u & 7;
            int gslot = slot ^ (row & 7);
            async16((char*)lds_a + u * 16, A + (size_t)(m0 + row) * K + kt + gslot * 8);
        }
#pragma unroll
        for (int i = 0; i < 2; ++i) {
            int u = i * 256 + t;
            int row = u >> 3, slot = u & 7;
            int gslot = slot ^ (row & 7);
            async16((char*)lds_b + u * 16, W + (size_t)(n0 + row) * K + kt + gslot * 8);
        }
        __syncthreads();
#pragma unroll
        for (int ks = 0; ks < 2; ++ks) {
            bf16x8 af[4], bfr[2];
#pragma unroll
            for (int mi = 0; mi < 4; ++mi) {
                int row = wm * 64 + mi * 16 + fr;
                int slot = (ks * 4 + hi) ^ (row & 7);
                af[mi] = *(const bf16x8*)((const char*)lds_a + row * 128 + slot * 16);
            }
#pragma unroll
            for (int ni = 0; ni < 2; ++ni) {
                int row = wn * 32 + ni * 16 + fr;
                int slot = (ks * 4 + hi) ^ (row & 7);
                bfr[ni] = *(const bf16x8*)((const char*)lds_b + row * 128 + slot * 16);
            }
#pragma unroll
            for (int mi = 0; mi < 4; ++mi)
#pragma unroll
                for (int ni = 0; ni < 2; ++ni)
                    acc[mi][ni] = __builtin_amdgcn_mfma_f32_16x16x32_bf16(bfr[ni], af[mi], acc[mi][ni], 0, 0, 0);
        }
    }
    const int rq4 = hi * 4;
#pragma unroll
    for (int mi = 0; mi < 4; ++mi) {
        int m = m0 + wm * 64 + mi * 16 + fr;
        size_t rowb = (size_t)m * N;
#pragma unroll
        for (int ni = 0; ni < 2; ++ni) {
            int nb = n0 + wn * 32 + ni * 16 + rq4;
            float v0 = acc[mi][ni][0], v1 = acc[mi][ni][1];
            float v2 = acc[mi][ni][2], v3 = acc[mi][ni][3];
            if (bias) {
                float4 b4 = *(const float4*)(bias + nb);
                v0 += b4.x; v1 += b4.y; v2 += b4.z; v3 += b4.w;
            }
            if (EPI == 1) { v0 = gelu_f(v0); v1 = gelu_f(v1); v2 = gelu_f(v2); v3 = gelu_f(v3); }
            if (EPI == 2) {
                float4* p = (float4*)((float*)Cout + rowb + nb);
                float4 o = *p;
                o.x += v0; o.y += v1; o.z += v2; o.w += v3;
                *p = o;
            } else {
                uint2 st;
                st.x = (unsigned)bfu(v0) | ((unsigned)bfu(v1) << 16);
                st.y = (unsigned)bfu(v2) | ((unsigned)bfu(v3) << 16);
                *(uint2*)((bf16*)Cout + rowb + nb) = st;
            }
        }
    }
}

extern "C" void kernel_launch(void* const* d_in, const int* in_sizes, int n_in,
                              void* d_out, int out_size, void* d_ws, size_t ws_size,
                              hipStream_t stream) {
    const float* x      = (const float*)d_in[0];
    const float* n1g    = (const float*)d_in[1];
    const float* n1b    = (const float*)d_in[2];
    const float* rpbt   = (const float*)d_in[3];
    const float* qkv_v  = (const float*)d_in[4];
    const float* qkv_u  = (const float*)d_in[5];
    const float* qkv_b  = (const float*)d_in[6];
    const float* proj_v = (const float*)d_in[7];
    const float* proj_u = (const float*)d_in[8];
    const float* proj_b = (const float*)d_in[9];
    const float* n2g    = (const float*)d_in[10];
    const float* n2b    = (const float*)d_in[11];
    const float* fc1_v  = (const float*)d_in[12];
    const float* fc1_u  = (const float*)d_in[13];
    const float* fc1_b  = (const float*)d_in[14];
    const float* fc2_v  = (const float*)d_in[15];
    const float* fc2_u  = (const float*)d_in[16];
    const float* fc2_b  = (const float*)d_in[17];

    char* ws = (char*)d_ws;
    bf16* wb = (bf16*)ws;
    bf16* w_qkv_v  = wb;
    bf16* w_qkv_u  = wb + 73728;
    bf16* w_proj_v = wb + 294912;
    bf16* w_proj_u = wb + 368640;
    bf16* w_fc1_v  = wb + 442368;
    bf16* w_fc1_u  = wb + 516096;
    bf16* w_fc2_v  = wb + 811008;
    bf16* w_fc2_u  = wb + 1105920;
    size_t off = (size_t)4 << 20;
    bf16* R1 = (bf16*)(ws + off); off += (size_t)MROWS * 1536 * 2;   // qkv / proj / mlp-hidden
    bf16* R2 = (bf16*)(ws + off); off += (size_t)MROWS * 384 * 2;    // ywin / o / z
    bf16* R3 = (bf16*)(ws + off);                                    // t1/t2/t3/t4 (M x 192)
    float* out = (float*)d_out;

    Cvt8 c;
    c.s[0] = qkv_v;  c.d[0] = w_qkv_v;  c.n[0] = 73728;
    c.s[1] = qkv_u;  c.d[1] = w_qkv_u;  c.n[1] = 221184;
    c.s[2] = proj_v; c.d[2] = w_proj_v; c.n[2] = 73728;
    c.s[3] = proj_u; c.d[3] = w_proj_u; c.n[3] = 73728;
    c.s[4] = fc1_v;  c.d[4] = w_fc1_v;  c.n[4] = 73728;
    c.s[5] = fc1_u;  c.d[5] = w_fc1_u;  c.n[5] = 294912;
    c.s[6] = fc2_v;  c.d[6] = w_fc2_v;  c.n[6] = 294912;
    c.s[7] = fc2_u;  c.d[7] = w_fc2_u;  c.n[7] = 73728;
    cvt8_k<<<dim3(288, 8), 256, 0, stream>>>(c);

    ln1_window_k<<<MROWS / 4, 256, 0, stream>>>(x, n1g, n1b, R2);
    gemm_bt<384, 0><<<dim3(3, 784), 256, 0, stream>>>(R2, w_qkv_v, nullptr, R3, 192);
    gemm_bt<192, 0><<<dim3(18, 784), 256, 0, stream>>>(R3, w_qkv_u, qkv_b, R1, 1152);
    attn_mfma_k<<<dim3(2048, 3), 256, 0, stream>>>(R1, rpbt, R2);
    gemm_bt<384, 0><<<dim3(3, 784), 256, 0, stream>>>(R2, w_proj_v, nullptr, R3, 192);
    gemm_bt<192, 0><<<dim3(6, 784), 256, 0, stream>>>(R3, w_proj_u, proj_b, R1, 384);
    resid_ln2_k<<<MROWS / 4, 256, 0, stream>>>(x, R1, n2g, n2b, out, R2);
    gemm_bt<384, 0><<<dim3(3, 784), 256, 0, stream>>>(R2, w_fc1_v, nullptr, R3, 192);
    gemm_bt<192, 1><<<dim3(24, 784), 256, 0, stream>>>(R3, w_fc1_u, fc1_b, R1, 1536);
    gemm_bt<1536, 0><<<dim3(3, 784), 256, 0, stream>>>(R1, w_fc2_v, nullptr, R3, 192);
    gemm_bt<192, 2><<<dim3(6, 784), 256, 0, stream>>>(R3, w_fc2_u, fc2_b, out, 384);
}